// Round 15
// baseline (347.607 us; speedup 1.0000x reference)
//
#include <hip/hip_runtime.h>

typedef __bf16 bf16;
typedef __bf16 bf16x8 __attribute__((ext_vector_type(8)));
typedef __bf16 bf16x4 __attribute__((ext_vector_type(4)));
typedef __bf16 bf16x2 __attribute__((ext_vector_type(2)));
typedef float f32x4 __attribute__((ext_vector_type(4)));
typedef float f32x2 __attribute__((ext_vector_type(2)));

#define DEVI __device__ __forceinline__

// problem constants
constexpr int Bc = 4, Sc = 1024, Hc = 2048, NHc = 16, HDc = 128;
constexpr int Tc = Bc * Sc;   // 4096
constexpr int Pc = NHc * HDc; // 2048
constexpr int SP = Sc + 1;    // padded tokens per batch (row 0 = cache)

DEVI void async16(const void* g, void* l) {
  __builtin_amdgcn_global_load_lds(
      (const __attribute__((address_space(1))) unsigned int*)g,
      (__attribute__((address_space(3))) unsigned int*)l, 16, 0, 0);
}

#define BAR() __builtin_amdgcn_s_barrier()
#define LGKM0()                                          \
  do {                                                   \
    asm volatile("s_waitcnt lgkmcnt(0)" ::: "memory");   \
    __builtin_amdgcn_sched_barrier(0);                   \
  } while (0)
#define VM0() asm volatile("s_waitcnt vmcnt(0)" ::: "memory")

// ---------------------------------------------------------------------------
// 8-phase GEMM, counted-vmcnt cross-tile pipeline (R12-verified ledger),
// templatized by THREADS = WM*WN*64 (R14: 128^2 tiles @ 256 thr -> 64KB LDS
// -> 2 blocks/CU; cross-block TLP hides the per-phase barrier drains).
// AMODE: 0 dense | 1 padded-token rows | 2 conv dual-tap (logical K=2*Kh).
// EPI: 0 bf16+bias | 1 V-transpose->vT | 2 RoPE(table)->qr,kr | 3 f32.
// ---------------------------------------------------------------------------
template <int WM, int WN, int MREP, int NREP, int EPI, int AMODE>
__global__ __launch_bounds__(WM * WN * 64, 2) void gemm8(
    const bf16* __restrict__ A, const bf16* __restrict__ W,
    void* __restrict__ C0, void* __restrict__ C1,
    const float* __restrict__ biasf, const f32x2* __restrict__ cst,
    int M, int N, int K) {
  constexpr int THREADS = WM * WN * 64;
  constexpr int BM = WM * MREP * 16;
  constexpr int BN = WN * NREP * 16;
  constexpr int MH = MREP / 2, NH = NREP / 2;
  constexpr int LA = BM * 4 / THREADS;   // per-thread loads per A half-tile
  constexpr int LB = BN * 4 / THREADS;
  constexpr int STG = (BM + BN) * 128;   // staging buffer bytes
  constexpr int OUTB = (EPI == 3) ? 4 : 2;
  constexpr int CBYTES = BM * BN * OUTB;
  constexpr int LDSB = (2 * STG > CBYTES) ? 2 * STG : CBYTES;
  __shared__ char lds[LDSB];

  const int nbx = N / BN;
  const int nwg = (M / BM) * nbx;
  int bx, by;
  if (nwg == 256 && nbx == 16) {
    const int xcd = blockIdx.x & 7, loc = blockIdx.x >> 3;
    by = (xcd >> 1) * 4 + (loc >> 3);
    bx = (xcd & 1) * 8 + (loc & 7);
  } else {
    const int wgid = (blockIdx.x & 7) * (nwg >> 3) + (blockIdx.x >> 3);
    bx = wgid % nbx;
    by = wgid / nbx;
  }
  const int m0 = by * BM, n0 = bx * BN;
  const int tid = threadIdx.x;
  const int w = tid >> 6, l = tid & 63;
  const int wm = w / WN, wn = w % WN;
  const int lr = l & 15, hi = l >> 4;

  // counted wait: leave exactly one half-tile (LL loads) in flight
  auto vminf = [&] {
    constexpr int LL = LA + LB;
    if constexpr (LL == 4)      asm volatile("s_waitcnt vmcnt(4)" ::: "memory");
    else if constexpr (LL == 3) asm volatile("s_waitcnt vmcnt(3)" ::: "memory");
    else if constexpr (LL == 2) asm volatile("s_waitcnt vmcnt(2)" ::: "memory");
    else                        asm volatile("s_waitcnt vmcnt(0)" ::: "memory");
  };

  auto aAddr = [&](int row, int t) -> const bf16* {
    const int m = m0 + row;
    if constexpr (AMODE == 0) {
      return A + (size_t)m * K + (t << 6);
    } else if constexpr (AMODE == 1) {
      return A + (size_t)((m >> 10) * SP + (m & 1023) + 1) * K + (t << 6);
    } else {
      const int Kh2 = K >> 1, nkh = Kh2 >> 6;
      const int tap = (t >= nkh) ? 1 : 0;
      return A + (size_t)((m >> 10) * SP + (m & 1023) + tap) * Kh2 +
             ((t - (tap ? nkh : 0)) << 6);
    }
  };

  auto stageA = [&](int buf, int t, int half) {
#pragma unroll
    for (int c = 0; c < LA; ++c) {
      const int ch = c * THREADS + tid;
      const int row = half * (BM / 2) + (ch >> 3);
      const int grp = ch & 7;
      async16(aAddr(row, t) + ((grp ^ (row & 7)) << 3),
              &lds[buf * STG + row * 128 + grp * 16]);
    }
  };
  auto stageB = [&](int buf, int t, int half) {
#pragma unroll
    for (int c = 0; c < LB; ++c) {
      const int ch = c * THREADS + tid;
      const int row = half * (BN / 2) + (ch >> 3);
      const int grp = ch & 7;
      async16(W + (size_t)(n0 + row) * K + (t << 6) + ((grp ^ (row & 7)) << 3),
              &lds[buf * STG + BM * 128 + row * 128 + grp * 16]);
    }
  };
  auto LD = [&](const char* Lp, int row, int g) -> bf16x8 {
    return *(const bf16x8*)(Lp + ((size_t)row << 7) + ((g ^ (row & 7)) << 4));
  };

#define QUAD(MB_, NB_, FB_)                                                     \
  do {                                                                          \
    __builtin_amdgcn_s_setprio(1);                                              \
    _Pragma("unroll") for (int m = 0; m < MH; ++m)                              \
      _Pragma("unroll") for (int n = 0; n < NH; ++n)                            \
        _Pragma("unroll") for (int kk = 0; kk < 2; ++kk)                        \
          acc[(MB_) + m][(NB_) + n] = __builtin_amdgcn_mfma_f32_16x16x32_bf16(  \
              fa[m][kk], FB_[n][kk], acc[(MB_) + m][(NB_) + n], 0, 0, 0);       \
    __builtin_amdgcn_s_setprio(0);                                              \
  } while (0)

  f32x4 acc[MREP][NREP] = {};
  bf16x8 fa[MH][2], fb0[NH][2], fb1[NH][2];
  const int nk = K >> 6;

  // prologue: tile0 fully (2*LL), tile1 half0 (LL); vmcnt(LL) retires tile0.
  stageA(0, 0, 0);
  stageB(0, 0, 0);
  stageA(0, 0, 1);
  stageB(0, 0, 1);
  stageA(1, 1, 0);
  stageB(1, 1, 0);
  vminf();
  BAR();

#pragma unroll 1
  for (int t = 0; t < nk; ++t) {
    const char* Lb = &lds[(t & 1) * STG];
    const int cur = t & 1, nbuf = cur ^ 1;
    const bool pf1 = (t + 1 < nk);
    // ---- phase 0: quadrant (0,0); stage A-half1 of t+1
#pragma unroll
    for (int m = 0; m < MH; ++m) {
      const int r = wm * (MREP * 16) + m * 16 + lr;
      fa[m][0] = LD(Lb, r, hi);
      fa[m][1] = LD(Lb, r, 4 + hi);
    }
#pragma unroll
    for (int n = 0; n < NH; ++n) {
      const int r = BM + wn * (NREP * 16) + n * 16 + lr;
      fb0[n][0] = LD(Lb, r, hi);
      fb0[n][1] = LD(Lb, r, 4 + hi);
    }
    if (pf1) stageA(nbuf, t + 1, 1);
    BAR();
    LGKM0();
    QUAD(0, 0, fb0);
    BAR();
    // ---- phase 1: quadrant (0,1); stage B-half1 of t+1
#pragma unroll
    for (int n = 0; n < NH; ++n) {
      const int r = BM + wn * (NREP * 16) + (NH + n) * 16 + lr;
      fb1[n][0] = LD(Lb, r, hi);
      fb1[n][1] = LD(Lb, r, 4 + hi);
    }
    if (pf1) stageB(nbuf, t + 1, 1);
    BAR();
    LGKM0();
    QUAD(0, NH, fb1);
    BAR();
    // ---- phase 2: quadrant (1,1); fa <- A half 1 (last reads of buf cur)
#pragma unroll
    for (int m = 0; m < MH; ++m) {
      const int r = wm * (MREP * 16) + (MH + m) * 16 + lr;
      fa[m][0] = LD(Lb, r, hi);
      fa[m][1] = LD(Lb, r, 4 + hi);
    }
    BAR();
    LGKM0();
    QUAD(MH, NH, fb1);
    BAR();
    // ---- phase 3: quadrant (1,0); stage t+2 half0 into cur; counted wait
    QUAD(MH, 0, fb0);
    if (t + 2 < nk) {
      stageA(cur, t + 2, 0);
      stageB(cur, t + 2, 0);
      vminf();  // all of t+1's 2*LL loads retired; t+2 half0 in flight
    } else {
      VM0();  // tail drain
    }
    BAR();
  }
#undef QUAD

  // =========================== fused epilogues ===========================
  if constexpr (EPI == 0) {
    bf16* cl = (bf16*)lds;
#pragma unroll
    for (int mi = 0; mi < MREP; ++mi)
#pragma unroll
      for (int ni = 0; ni < NREP; ++ni) {
        const int col = wn * (NREP * 16) + ni * 16 + lr;
        const float bv = biasf ? biasf[n0 + col] : 0.f;
#pragma unroll
        for (int j = 0; j < 4; ++j) {
          const int row = wm * (MREP * 16) + mi * 16 + (hi << 2) + j;
          cl[row * BN + ((((col >> 3) ^ (row & 7)) << 3) | (col & 7))] =
              (bf16)(acc[mi][ni][j] + bv);
        }
      }
    __syncthreads();
    constexpr int GPR = BN / 8;
    constexpr int PT = BM * GPR / THREADS;
#pragma unroll
    for (int c = 0; c < PT; ++c) {
      const int ch = c * THREADS + tid;
      const int row = ch / GPR, g = ch % GPR;
      bf16x8 vv = *(const bf16x8*)&cl[row * BN + ((g ^ (row & 7)) << 3)];
      *(bf16x8*)&((bf16*)C0)[(size_t)(m0 + row) * N + n0 + g * 8] = vv;
    }
  } else if constexpr (EPI == 1) {
    // V-transpose epilogue (BN == 128: tile spans exactly one head)
    bf16* cl = (bf16*)lds;
#pragma unroll
    for (int mi = 0; mi < MREP; ++mi)
#pragma unroll
      for (int ni = 0; ni < NREP; ++ni) {
        const int col = wn * (NREP * 16) + ni * 16 + lr;  // d
#pragma unroll
        for (int j = 0; j < 4; ++j) {
          const int row = wm * (MREP * 16) + mi * 16 + (hi << 2) + j;  // s-off
          cl[col * BM + ((((row >> 3) ^ (col & 7)) << 3) | (row & 7))] =
              (bf16)acc[mi][ni][j];
        }
      }
    __syncthreads();
    const int s0 = m0 & 1023, bq = m0 >> 10;
    bf16* vT = (bf16*)C0;
    const size_t vbase = (((size_t)(bq * 16 + (n0 >> 7)) * 128) << 10) + s0;
    constexpr int GPR = BM / 8;
    constexpr int PT = BN * GPR / THREADS;
#pragma unroll
    for (int c = 0; c < PT; ++c) {
      const int ch = c * THREADS + tid;
      const int d = ch / GPR, g = ch % GPR;
      bf16x8 vv = *(const bf16x8*)&cl[d * BM + ((g ^ (d & 7)) << 3)];
      *(bf16x8*)&vT[vbase + ((size_t)d << 10) + g * 8] = vv;
    }
  } else if constexpr (EPI == 2) {
    // RoPE epilogue (table-driven)
    bf16* cl = (bf16*)lds;
#pragma unroll
    for (int mi = 0; mi < MREP; ++mi)
#pragma unroll
      for (int ni = 0; ni < NREP; ++ni) {
        const int col = wn * (NREP * 16) + ni * 16 + lr;
#pragma unroll
        for (int j = 0; j < 4; ++j) {
          const int row = wm * (MREP * 16) + mi * 16 + (hi << 2) + j;
          cl[row * BN + ((((col >> 3) ^ (row & 7)) << 3) | (col & 7))] =
              (bf16)acc[mi][ni][j];
        }
      }
    __syncthreads();
    const int s0 = m0 & 1023, bq = m0 >> 10, head = n0 >> 8;
    bf16* qr = (bf16*)C0;
    bf16* kr = (bf16*)C1;
    const size_t qbase = ((size_t)((bq * 16 + head) * 1024 + s0) << 7);
    constexpr int GPR = BN / 8;
    constexpr int PT = BM * GPR / THREADS;
#pragma unroll
    for (int c = 0; c < PT; ++c) {
      const int ch = c * THREADS + tid;
      const int row = ch / GPR, g = ch % GPR;
      const int cc = g * 8;
      const int isk = cc >> 7, dd = cc & 127;
      bf16x8 vv = *(const bf16x8*)&cl[row * BN + ((g ^ (row & 7)) << 3)];
      bf16x8 out;
      if (dd < 64) {
        bf16x8 pp = *(const bf16x8*)&cl[row * BN + (((g ^ 4) ^ (row & 7)) << 3)];
        const f32x2* cp = &cst[(s0 + row) * 64 + dd];
#pragma unroll
        for (int e = 0; e < 8; ++e) {
          const f32x2 cs = cp[e];
          const float pv = (dd < 32) ? -(float)pp[e] : (float)pp[e];
          out[e] = (bf16)((float)vv[e] * cs[0] + pv * cs[1]);
        }
      } else {
        out = vv;
      }
      bf16* dst = isk ? kr : qr;
      *(bf16x8*)&dst[qbase + ((size_t)row << 7) + dd] = out;
    }
  } else {
    float* cl = (float*)lds;
#pragma unroll
    for (int mi = 0; mi < MREP; ++mi)
#pragma unroll
      for (int ni = 0; ni < NREP; ++ni) {
        const int col = wn * (NREP * 16) + ni * 16 + lr;
        const float bv = biasf ? biasf[n0 + col] : 0.f;
#pragma unroll
        for (int j = 0; j < 4; ++j) {
          const int row = wm * (MREP * 16) + mi * 16 + (hi << 2) + j;
          cl[row * BN + ((((col >> 2) ^ (row & 7)) << 2) | (col & 3))] =
              acc[mi][ni][j] + bv;
        }
      }
    __syncthreads();
    constexpr int GPR = BN / 4;
    constexpr int PT = BM * GPR / THREADS;
#pragma unroll
    for (int c = 0; c < PT; ++c) {
      const int ch = c * THREADS + tid;
      const int row = ch / GPR, g = ch % GPR;
      f32x4 vv = *(const f32x4*)&cl[row * BN + ((g ^ (row & 7)) << 2)];
      *(f32x4*)&((float*)C0)[(size_t)(m0 + row) * N + n0 + g * 4] = vv;
    }
  }
}

// ---------------------------------------------------------------------------
// 2-phase pipelined GEMM + LDS-staged epilogue — conv1.
// AMODE 2: dual-tap padded rows (logical K = 2*Kh). OUTPAD: write padded o1p.
// ---------------------------------------------------------------------------
template <int WM, int WN, int MREP, int NREP, int AMODE, bool OUTPAD>
__global__ __launch_bounds__(WM * WN * 64, 2) void gemm_pipe(
    const bf16* __restrict__ A, const bf16* __restrict__ W, void* __restrict__ Cout,
    const float* __restrict__ bias, int M, int N, int K) {
  constexpr int BM = WM * MREP * 16;
  constexpr int BN = WN * NREP * 16;
  constexpr int THREADS = WM * WN * 64;
  constexpr int ROWS = BM + BN;
  constexpr int CHA = BM * 4 / THREADS;
  constexpr int CHB = BN * 4 / THREADS;
  static_assert(CHA + CHB == 4, "vmcnt ledger assumes 4 loads/thread/stage");
  __shared__ bf16 lds[4][ROWS * 32];
  static_assert(BM * BN * 2 <= sizeof(lds), "C tile must fit LDS for epilogue");

  const int nbx = N / BN;
  const int nwg = (M / BM) * nbx;
  const int wgid = (blockIdx.x & 7) * (nwg >> 3) + (blockIdx.x >> 3);
  const int bx = wgid % nbx, by = wgid / nbx;
  const int m0 = by * BM, n0 = bx * BN;
  const int tid = threadIdx.x;
  const int w = tid >> 6, l = tid & 63;
  const int wm = w / WN, wn = w % WN;
  const int lr = l & 15;
  const int hi = l >> 4;

  auto aAddr = [&](int row, int t) -> const bf16* {
    const int m = m0 + row;
    if constexpr (AMODE == 2) {
      const int Kh2 = K >> 1, nkh = Kh2 >> 5;
      const int tap = (t >= nkh) ? 1 : 0;
      return A + (size_t)((m >> 10) * SP + (m & 1023) + tap) * Kh2 +
             ((t - (tap ? nkh : 0)) << 5);
    } else {
      return A + (size_t)m * K + (t << 5);
    }
  };

  auto stage = [&](int slot, int t) {
    const int k0 = t << 5;
#pragma unroll
    for (int c = 0; c < CHA; ++c) {
      const int ch = c * THREADS + tid;
      const int row = ch >> 2, cg = ch & 3;
      const int gc = (cg ^ ((row >> 1) & 3)) << 3;
      async16(aAddr(row, t) + gc, (char*)&lds[slot][0] + ch * 16);
    }
#pragma unroll
    for (int c = 0; c < CHB; ++c) {
      const int ch = c * THREADS + tid;
      const int row = ch >> 2, cg = ch & 3;
      const int gc = (cg ^ ((row >> 1) & 3)) << 3;
      async16(W + (size_t)(n0 + row) * K + k0 + gc,
              (char*)&lds[slot][0] + (BM * 4 + ch) * 16);
    }
  };

  f32x4 acc[MREP][NREP] = {};
  const int nk = K >> 5;

  stage(0, 0);
  stage(1, 1);
  stage(2, 2);
  asm volatile("s_waitcnt vmcnt(8)" ::: "memory");
  __builtin_amdgcn_s_barrier();
  __builtin_amdgcn_sched_barrier(0);

  bf16x8 fAc[MREP], fBc[NREP], fAn[MREP], fBn[NREP];
  {
    const char* nb = (const char*)&lds[0][0];
#pragma unroll
    for (int mi = 0; mi < MREP; ++mi) {
      const int r = wm * (MREP * 16) + mi * 16 + lr;
      fAc[mi] = *(const bf16x8*)(nb + r * 64 + ((hi ^ ((r >> 1) & 3)) << 4));
    }
#pragma unroll
    for (int ni = 0; ni < NREP; ++ni) {
      const int r = BM + wn * (NREP * 16) + ni * 16 + lr;
      fBc[ni] = *(const bf16x8*)(nb + r * 64 + ((hi ^ ((r >> 1) & 3)) << 4));
    }
  }

#define GSTEP(T_, CA, CB, NA, NB)                                              \
  do {                                                                         \
    if ((T_) + 2 < nk) asm volatile("s_waitcnt vmcnt(4)" ::: "memory");        \
    else               asm volatile("s_waitcnt vmcnt(0)" ::: "memory");        \
    __builtin_amdgcn_s_barrier();                                              \
    __builtin_amdgcn_sched_barrier(0);                                         \
    if ((T_) + 3 < nk) stage(((T_) + 3) & 3, (T_) + 3);                        \
    if ((T_) + 1 < nk) {                                                       \
      const char* nb = (const char*)&lds[((T_) + 1) & 3][0];                   \
      _Pragma("unroll") for (int mi = 0; mi < MREP; ++mi) {                    \
        const int r = wm * (MREP * 16) + mi * 16 + lr;                         \
        NA[mi] = *(const bf16x8*)(nb + r * 64 + ((hi ^ ((r >> 1) & 3)) << 4)); \
      }                                                                        \
      _Pragma("unroll") for (int ni = 0; ni < NREP; ++ni) {                    \
        const int r = BM + wn * (NREP * 16) + ni * 16 + lr;                    \
        NB[ni] = *(const bf16x8*)(nb + r * 64 + ((hi ^ ((r >> 1) & 3)) << 4)); \
      }                                                                        \
    }                                                                          \
    __builtin_amdgcn_s_setprio(1);                                             \
    _Pragma("unroll") for (int mi = 0; mi < MREP; ++mi)                        \
      _Pragma("unroll") for (int ni = 0; ni < NREP; ++ni)                      \
        acc[mi][ni] =                                                          \
            __builtin_amdgcn_mfma_f32_16x16x32_bf16(CA[mi], CB[ni], acc[mi][ni], 0, 0, 0); \
    __builtin_amdgcn_s_setprio(0);                                             \
  } while (0)

  for (int t = 0; t < nk; t += 2) {
    GSTEP(t, fAc, fBc, fAn, fBn);
    GSTEP(t + 1, fAn, fBn, fAc, fBc);
  }
#undef GSTEP

  // ---- LDS-staged coalesced epilogue (bf16, optionally padded rows) ----
  __syncthreads();
  {
    bf16* cl = (bf16*)&lds[0][0];
#pragma unroll
    for (int mi = 0; mi < MREP; ++mi) {
#pragma unroll
      for (int ni = 0; ni < NREP; ++ni) {
        const int col = wn * (NREP * 16) + ni * 16 + lr;
        const float bv = bias ? bias[n0 + col] : 0.f;
#pragma unroll
        for (int j = 0; j < 4; ++j) {
          const int row = wm * (MREP * 16) + mi * 16 + (hi << 2) + j;
          cl[row * BN + ((((col >> 3) ^ (row & 7)) << 3) | (col & 7))] =
              (bf16)(acc[mi][ni][j] + bv);
        }
      }
    }
    __syncthreads();
    constexpr int GPR = BN / 8;
    constexpr int PT = BM * GPR / THREADS;
#pragma unroll
    for (int c = 0; c < PT; ++c) {
      const int ch = c * THREADS + tid;
      const int row = ch / GPR, g = ch % GPR;
      const int mr = m0 + row;
      const size_t orow = OUTPAD ? (size_t)((mr >> 10) * SP + (mr & 1023) + 1)
                                 : (size_t)mr;
      bf16x8 vv = *(const bf16x8*)&cl[row * BN + ((g ^ (row & 7)) << 3)];
      *(bf16x8*)&((bf16*)Cout)[orow * N + n0 + g * 8] = vv;
    }
  }
}

// ---------------------------------------------------------------------------
// fp32 -> bf16 weight conversion (vectorized by 4)
// ---------------------------------------------------------------------------
__global__ void k_f2b4(const float* __restrict__ in, bf16* __restrict__ out, int n4) {
  int i = blockIdx.x * 256 + threadIdx.x;
  if (i >= n4) return;
  float4 v = ((const float4*)in)[i];
  bf16x4 o = {(bf16)v.x, (bf16)v.y, (bf16)v.z, (bf16)v.w};
  ((bf16x4*)out)[i] = o;
}

// de-interleave conv weight (O,Hd,2) fp32 -> (O, 2, Hd) bf16
__global__ void k_deint(const float* __restrict__ in, bf16* __restrict__ out,
                        int O, int Hd) {
  int i = blockIdx.x * 256 + threadIdx.x;  // < O*Hd/2
  if (i >= O * (Hd >> 1)) return;
  int o = i / (Hd >> 1), h0 = (i % (Hd >> 1)) * 2;
  float4 v = *(const float4*)&in[(size_t)o * Hd * 2 + h0 * 2];
  bf16x2 t0 = {(bf16)v.x, (bf16)v.z};   // tap0: h0, h0+1
  bf16x2 t1 = {(bf16)v.y, (bf16)v.w};   // tap1
  *(bf16x2*)&out[(size_t)o * 2 * Hd + h0] = t0;
  *(bf16x2*)&out[(size_t)o * 2 * Hd + Hd + h0] = t1;
}

// build padded hsbp (B, S+1, H): row 0 = lf1, rows 1..S = bf16(hid);
// prefill o1p row 0 = lf2; ALSO build trig table (folded k_trig).
__global__ void k_build_hsbp(const float* __restrict__ hid, const float* __restrict__ lf1,
                             const float* __restrict__ lf2, const float* __restrict__ rot,
                             bf16* __restrict__ hsbp, bf16* __restrict__ o1p,
                             f32x2* __restrict__ cst) {
  int idx = blockIdx.x * 256 + threadIdx.x;  // < T*H
  int t = idx >> 11, h = idx & 2047;
  int b = t >> 10, s = t & 1023;
  hsbp[((size_t)(b * SP + s + 1) << 11) + h] = (bf16)hid[idx];
  if (idx < Bc * Hc) {
    int bb = idx >> 11, hh = idx & 2047;
    hsbp[((size_t)(bb * SP) << 11) + hh] = (bf16)lf1[idx];
  }
  if (idx < Bc * 1024) {
    int bb = idx >> 10, cc = idx & 1023;
    o1p[((size_t)(bb * SP) << 10) + cc] = (bf16)lf2[idx];
  }
  if (idx < Sc * 64) {
    float f = rot[idx];
    f32x2 cs = {cosf(f), sinf(f)};
    cst[idx] = cs;
  }
}

// lf = rmsnorm(o2 + hid) * g   (one block per row, 256 thr x 8 elems)
__global__ __launch_bounds__(256) void k_rmsnorm(const bf16* __restrict__ o2,
                                                 const float* __restrict__ hid,
                                                 const float* __restrict__ g,
                                                 bf16* __restrict__ lf) {
  int t = blockIdx.x, tid = threadIdx.x;
  size_t base = ((size_t)t << 11) + tid * 8;
  bf16x8 ov = *(const bf16x8*)&o2[base];
  const float* hp = &hid[base];
  float vals[8];
  float ss = 0.f;
#pragma unroll
  for (int i = 0; i < 8; ++i) {
    float x = (float)ov[i] + hp[i];
    vals[i] = x;
    ss += x * x;
  }
#pragma unroll
  for (int off = 1; off < 64; off <<= 1) ss += __shfl_xor(ss, off);
  __shared__ float red[4];
  if ((tid & 63) == 0) red[tid >> 6] = ss;
  __syncthreads();
  float tot = red[0] + red[1] + red[2] + red[3];
  float inv = rsqrtf(tot * (1.f / 2048.f) + 1e-6f);
  bf16x8 o;
#pragma unroll
  for (int i = 0; i < 8; ++i) o[i] = (bf16)(vals[i] * inv * g[tid * 8 + i]);
  *(bf16x8*)&lf[base] = o;
}

// ---------------------------------------------------------------------------
// causal flash attention v3: LDS-staged K/V (dbuf), balanced q-tile pairs,
// XCD-local (b,h) mapping, setprio around MFMA clusters, defer-max (THR=8).
// ---------------------------------------------------------------------------
__global__ __launch_bounds__(256, 2) void k_attn(const bf16* __restrict__ qr,
                                                 const bf16* __restrict__ kr,
                                                 const bf16* __restrict__ vT,
                                                 bf16* __restrict__ att) {
  __shared__ bf16 Ks[2][64 * 128];
  __shared__ bf16 Vs[2][128 * 64];
  __shared__ bf16 plds[4][16 * 64];
  const int bid = blockIdx.x;
  const int xcd = bid & 7, jj = bid >> 3;
  const int bn = xcd * 8 + (jj >> 3);
  const int pr = jj & 7;
  const int tid = threadIdx.x, w = tid >> 6, l = tid & 63;
  const int lr = l & 15, hi = l >> 4;
  const bf16* kb = kr + ((size_t)bn << 17);
  const bf16* vb = vT + ((size_t)bn << 17);
  const int b = bn >> 4, hh = bn & 15;
  const float scaling = 0.08838834764831845f;
  const float THR = 8.f;

  auto stage = [&](int buf, int kt) {
#pragma unroll
    for (int c = 0; c < 4; ++c) {
      int chunk = c * 256 + tid;
      int prow = chunk >> 4, pcg = chunk & 15;
      async16(kb + ((size_t)(kt * 64 + prow) << 7) + ((pcg ^ (prow & 7)) << 3),
              (char*)&Ks[buf][0] + chunk * 16);
    }
#pragma unroll
    for (int c = 0; c < 4; ++c) {
      int chunk = c * 256 + tid;
      int prow = chunk >> 3, pcg = chunk & 7;
      async16(vb + ((size_t)prow << 10) + kt * 64 + ((pcg ^ (prow & 7)) << 3),
              (char*)&Vs[buf][0] + chunk * 16);
    }
  };

#pragma unroll 1
  for (int phase = 0; phase < 2; ++phase) {
    const int qt = phase ? (15 - pr) : pr;
    const int qg0 = qt * 64 + w * 16;
    const bf16* qb = qr + ((size_t)(bn * 1024 + qg0) << 7);
    bf16x8 qf[4];
#pragma unroll
    for (int ks = 0; ks < 4; ++ks) qf[ks] = *(const bf16x8*)&qb[lr * 128 + ks * 32 + hi * 8];
    f32x4 oacc[8] = {};
    float mrow[4] = {-1e30f, -1e30f, -1e30f, -1e30f};
    float lrow[4] = {0.f, 0.f, 0.f, 0.f};
    const int nkb = qt + 1;

    stage(0, 0);
    __syncthreads();

    for (int kbt = 0; kbt < nkb; ++kbt) {
      const int cur = kbt & 1;
      if (kbt + 1 < nkb) stage(cur ^ 1, kbt + 1);

      f32x4 sacc[4] = {};
      __builtin_amdgcn_s_setprio(1);
#pragma unroll
      for (int n = 0; n < 4; ++n) {
        const int krow = n * 16 + lr;
#pragma unroll
        for (int ks = 0; ks < 4; ++ks) {
          bf16x8 kf = *(const bf16x8*)&Ks[cur][(krow << 7) + ((((ks << 2) | hi) ^ (krow & 7)) << 3)];
          sacc[n] = __builtin_amdgcn_mfma_f32_16x16x32_bf16(qf[ks], kf, sacc[n], 0, 0, 0);
        }
      }
      __builtin_amdgcn_s_setprio(0);
      const bool needmask = (kbt * 64 + 63 > qg0);
#pragma unroll
      for (int n = 0; n < 4; ++n) {
        int kg = kbt * 64 + n * 16 + lr;
#pragma unroll
        for (int j = 0; j < 4; ++j) {
          float sv = sacc[n][j] * scaling;
          if (needmask && kg > qg0 + hi * 4 + j) sv = -1e30f;
          sacc[n][j] = sv;
        }
      }
      float pm[4];
#pragma unroll
      for (int j = 0; j < 4; ++j) {
        float p = fmaxf(fmaxf(sacc[0][j], sacc[1][j]), fmaxf(sacc[2][j], sacc[3][j]));
        p = fmaxf(p, __shfl_xor(p, 1));
        p = fmaxf(p, __shfl_xor(p, 2));
        p = fmaxf(p, __shfl_xor(p, 4));
        p = fmaxf(p, __shfl_xor(p, 8));
        pm[j] = p;
      }
      float sf[4] = {1.f, 1.f, 1.f, 1.f};
      bool needup = (pm[0] > mrow[0] + THR) || (pm[1] > mrow[1] + THR) ||
                    (pm[2] > mrow[2] + THR) || (pm[3] > mrow[3] + THR);
      if (__any(needup)) {
#pragma unroll
        for (int j = 0; j < 4; ++j) {
          float mn = fmaxf(mrow[j], pm[j]);
          sf[j] = __expf(mrow[j] - mn);
          mrow[j] = mn;
        }
#pragma unroll
        for (int dt = 0; dt < 8; ++dt)
#pragma unroll
          for (int j = 0; j < 4; ++j) oacc[dt][j] *= sf[j];
      }
#pragma unroll
      for (int n = 0; n < 4; ++n)
#pragma unroll
        for (int j = 0; j < 4; ++j) sacc[n][j] = __expf(sacc[n][j] - mrow[j]);
#pragma unroll
      for (int j = 0; j < 4; ++j) {
        float ps = sacc[0][j] + sacc[1][j] + sacc[2][j] + sacc[3][j];
        ps += __shfl_xor(ps, 1);
        ps += __shfl_xor(ps, 2);
        ps += __shfl_xor(ps, 4);
        ps += __shfl_xor(ps, 8);
        lrow[j] = lrow[j] * sf[j] + ps;
      }
#pragma unroll
      for (int n = 0; n < 4; ++n)
#pragma unroll
        for (int j = 0; j < 4; ++j)
          plds[w][(hi * 4 + j) * 64 + n * 16 + lr] = (bf16)sacc[n][j];
      asm volatile("s_waitcnt lgkmcnt(0)" ::: "memory");
      __builtin_amdgcn_s_setprio(1);
#pragma unroll
      for (int ks2 = 0; ks2 < 2; ++ks2) {
        bf16x8 pf = *(const bf16x8*)&plds[w][lr * 64 + ks2 * 32 + hi * 8];
#pragma unroll
        for (int dt = 0; dt < 8; ++dt) {
          const int vrow = dt * 16 + lr;
          bf16x8 vf = *(const bf16x8*)&Vs[cur][(vrow << 6) + ((((ks2 << 2) | hi) ^ (lr & 7)) << 3)];
          oacc[dt] = __builtin_amdgcn_mfma_f32_16x16x32_bf16(pf, vf, oacc[dt], 0, 0, 0);
        }
      }
      __builtin_amdgcn_s_setprio(0);
      __syncthreads();
    }

#pragma unroll
    for (int j = 0; j < 4; ++j) {
      float inv = 1.f / lrow[j];
      int qg = qg0 + hi * 4 + j;
      size_t obase = ((size_t)(b * 1024 + qg) << 11) + hh * 128;
#pragma unroll
      for (int dt = 0; dt < 8; ++dt) att[obase + dt * 16 + lr] = (bf16)(oacc[dt][j] * inv);
    }
  }
}

// ---------------------------------------------------------------------------
// Workspace plan (~124 MB, sequential liveness):
//   0-16    Wslot (Wv, W1d, W2d, Wqk(16), Wo)
//   16-34   hsbp (B,S+1,H) 16.8MB  [dead after conv1] -> att (16MB)
//   34-43   o1p (B,S+1,1024) 8.4MB [dead after conv2]
//   43-59   o2
//   59-75   lfb
//   75-91   vT
//   91-107  qr
//   107-123 kr
//   123-123.5 cst
// ---------------------------------------------------------------------------
extern "C" void kernel_launch(void* const* d_in, const int* in_sizes, int n_in,
                              void* d_out, int out_size, void* d_ws, size_t ws_size,
                              hipStream_t stream) {
  const float* hid = (const float*)d_in[1];
  const float* rot = (const float*)d_in[2];
  const float* lf1 = (const float*)d_in[3];
  const float* lf2 = (const float*)d_in[4];
  const float* Wqk = (const float*)d_in[5];
  const float* Wv  = (const float*)d_in[6];
  const float* Wo  = (const float*)d_in[7];
  const float* c1w = (const float*)d_in[8];
  const float* c1b = (const float*)d_in[9];
  const float* c2w = (const float*)d_in[10];
  const float* c2b = (const float*)d_in[11];
  const float* lng = (const float*)d_in[12];
  float* outp = (float*)d_out;
  char* ws = (char*)d_ws;

  const size_t MB = 1ull << 20;
  bf16* Wslot = (bf16*)(ws + 0 * MB);
  bf16* hsbp  = (bf16*)(ws + 16 * MB);
  bf16* att   = (bf16*)(ws + 16 * MB);   // alias (hsbp dead after conv1)
  bf16* o1p   = (bf16*)(ws + 34 * MB);
  bf16* o2    = (bf16*)(ws + 43 * MB);
  bf16* lfb   = (bf16*)(ws + 59 * MB);
  bf16* vT    = (bf16*)(ws + 75 * MB);
  bf16* qr    = (bf16*)(ws + 91 * MB);
  bf16* kr    = (bf16*)(ws + 107 * MB);
  f32x2* cst  = (f32x2*)(ws + 123 * MB);

  auto f2b = [&](const float* in, bf16* out, int n) {
    int n4 = n / 4;
    k_f2b4<<<(n4 + 255) / 256, 256, 0, stream>>>(in, out, n4);
  };

  // 0. padded inputs + trig table (one kernel)
  k_build_hsbp<<<Tc * Hc / 256, 256, 0, stream>>>(hid, lf1, lf2, rot, hsbp, o1p, cst);

  // 1. v = hs @ Wv.T (padded rows), fused V-transpose -> vT.
  //    R14: 128^2 tiles @ 256 thr, 64KB LDS -> 2 blocks/CU; grid 512.
  f2b(Wv, Wslot, 2048 * 2048);
  gemm8<2, 2, 4, 4, 1, 1><<<512, 256, 0, stream>>>(hsbp, Wslot, vT, nullptr, nullptr,
                                                   nullptr, Tc, Pc, Hc);

  // 2. conv1: dual-tap GEMM (logical K=4096 over hsbp taps) -> padded o1p
  k_deint<<<(1024 * 1024 + 255) / 256, 256, 0, stream>>>(c1w, Wslot, 1024, 2048);
  gemm_pipe<2, 2, 4, 4, 2, true><<<256, 256, 0, stream>>>(hsbp, Wslot, o1p, c1b,
                                                          Tc, 1024, 4096);

  // 3. conv2: dual-tap GEMM (logical K=2048 over o1p taps) -> o2 (dense); 128^2
  k_deint<<<(2048 * 512 + 255) / 256, 256, 0, stream>>>(c2w, Wslot, 2048, 1024);
  gemm8<2, 2, 4, 4, 0, 2><<<512, 256, 0, stream>>>(o1p, Wslot, o2, nullptr, c2b,
                                                   nullptr, Tc, 2048, 2048);

  // 4. residual + rmsnorm
  k_rmsnorm<<<Tc, 256, 0, stream>>>(o2, hid, lng, lfb);

  // 5. qk projection (256^2, 512 thr), fused RoPE epilogue -> qr, kr
  f2b(Wqk, Wslot, 4096 * 2048);
  gemm8<2, 4, 8, 4, 2, 0><<<256, 512, 0, stream>>>(lfb, Wslot, qr, kr, nullptr, cst,
                                                   Tc, 4096, Hc);

  // 6. attention
  k_attn<<<Bc * NHc * 8, 256, 0, stream>>>(qr, kr, vT, att);

  // 7. output projection (fp32 out); 128^2
  f2b(Wo, Wslot, 2048 * 2048);
  gemm8<2, 2, 4, 4, 3, 0><<<512, 256, 0, stream>>>(att, Wslot, outp, nullptr, nullptr,
                                                   nullptr, Tc, 2048, 2048);
}

// Round 16
// 334.560 us; speedup vs baseline: 1.0390x; 1.0390x over previous
//
#include <hip/hip_runtime.h>

typedef __bf16 bf16;
typedef __bf16 bf16x8 __attribute__((ext_vector_type(8)));
typedef __bf16 bf16x4 __attribute__((ext_vector_type(4)));
typedef __bf16 bf16x2 __attribute__((ext_vector_type(2)));
typedef float f32x4 __attribute__((ext_vector_type(4)));
typedef float f32x2 __attribute__((ext_vector_type(2)));

#define DEVI __device__ __forceinline__

// problem constants
constexpr int Bc = 4, Sc = 1024, Hc = 2048, NHc = 16, HDc = 128;
constexpr int Tc = Bc * Sc;   // 4096
constexpr int Pc = NHc * HDc; // 2048
constexpr int SP = Sc + 1;    // padded tokens per batch (row 0 = cache)

DEVI void async16(const void* g, void* l) {
  __builtin_amdgcn_global_load_lds(
      (const __attribute__((address_space(1))) unsigned int*)g,
      (__attribute__((address_space(3))) unsigned int*)l, 16, 0, 0);
}

#define BAR() __builtin_amdgcn_s_barrier()
#define LGKM0()                                          \
  do {                                                   \
    asm volatile("s_waitcnt lgkmcnt(0)" ::: "memory");   \
    __builtin_amdgcn_sched_barrier(0);                   \
  } while (0)
#define VM0() asm volatile("s_waitcnt vmcnt(0)" ::: "memory")

// ---------------------------------------------------------------------------
// 8-phase GEMM, counted-vmcnt cross-tile pipeline (R12-verified ledger),
// templatized by THREADS = WM*WN*64.
// AMODE: 0 dense | 1 padded-token rows | 2 conv dual-tap (logical K=2*Kh).
// EPI: 0 bf16+bias | 1 V-transpose->vT | 2 RoPE(table)->qr,kr | 3 f32.
// ---------------------------------------------------------------------------
template <int WM, int WN, int MREP, int NREP, int EPI, int AMODE>
__global__ __launch_bounds__(WM * WN * 64, 2) void gemm8(
    const bf16* __restrict__ A, const bf16* __restrict__ W,
    void* __restrict__ C0, void* __restrict__ C1,
    const float* __restrict__ biasf, const f32x2* __restrict__ cst,
    int M, int N, int K) {
  constexpr int THREADS = WM * WN * 64;
  constexpr int BM = WM * MREP * 16;
  constexpr int BN = WN * NREP * 16;
  constexpr int MH = MREP / 2, NH = NREP / 2;
  constexpr int LA = BM * 4 / THREADS;   // per-thread loads per A half-tile
  constexpr int LB = BN * 4 / THREADS;
  constexpr int STG = (BM + BN) * 128;   // staging buffer bytes
  constexpr int OUTB = (EPI == 3) ? 4 : 2;
  constexpr int CBYTES = BM * BN * OUTB;
  constexpr int LDSB = (2 * STG > CBYTES) ? 2 * STG : CBYTES;
  __shared__ char lds[LDSB];

  const int nbx = N / BN;
  const int nwg = (M / BM) * nbx;
  int bx, by;
  if (nwg == 256 && nbx == 16) {
    const int xcd = blockIdx.x & 7, loc = blockIdx.x >> 3;
    by = (xcd >> 1) * 4 + (loc >> 3);
    bx = (xcd & 1) * 8 + (loc & 7);
  } else {
    const int wgid = (blockIdx.x & 7) * (nwg >> 3) + (blockIdx.x >> 3);
    bx = wgid % nbx;
    by = wgid / nbx;
  }
  const int m0 = by * BM, n0 = bx * BN;
  const int tid = threadIdx.x;
  const int w = tid >> 6, l = tid & 63;
  const int wm = w / WN, wn = w % WN;
  const int lr = l & 15, hi = l >> 4;

  // counted wait: leave exactly one half-tile (LL loads) in flight
  auto vminf = [&] {
    constexpr int LL = LA + LB;
    if constexpr (LL == 4)      asm volatile("s_waitcnt vmcnt(4)" ::: "memory");
    else if constexpr (LL == 3) asm volatile("s_waitcnt vmcnt(3)" ::: "memory");
    else if constexpr (LL == 2) asm volatile("s_waitcnt vmcnt(2)" ::: "memory");
    else                        asm volatile("s_waitcnt vmcnt(0)" ::: "memory");
  };

  auto aAddr = [&](int row, int t) -> const bf16* {
    const int m = m0 + row;
    if constexpr (AMODE == 0) {
      return A + (size_t)m * K + (t << 6);
    } else if constexpr (AMODE == 1) {
      return A + (size_t)((m >> 10) * SP + (m & 1023) + 1) * K + (t << 6);
    } else {
      const int Kh2 = K >> 1, nkh = Kh2 >> 6;
      const int tap = (t >= nkh) ? 1 : 0;
      return A + (size_t)((m >> 10) * SP + (m & 1023) + tap) * Kh2 +
             ((t - (tap ? nkh : 0)) << 6);
    }
  };

  auto stageA = [&](int buf, int t, int half) {
#pragma unroll
    for (int c = 0; c < LA; ++c) {
      const int ch = c * THREADS + tid;
      const int row = half * (BM / 2) + (ch >> 3);
      const int grp = ch & 7;
      async16(aAddr(row, t) + ((grp ^ (row & 7)) << 3),
              &lds[buf * STG + row * 128 + grp * 16]);
    }
  };
  auto stageB = [&](int buf, int t, int half) {
#pragma unroll
    for (int c = 0; c < LB; ++c) {
      const int ch = c * THREADS + tid;
      const int row = half * (BN / 2) + (ch >> 3);
      const int grp = ch & 7;
      async16(W + (size_t)(n0 + row) * K + (t << 6) + ((grp ^ (row & 7)) << 3),
              &lds[buf * STG + BM * 128 + row * 128 + grp * 16]);
    }
  };
  auto LD = [&](const char* Lp, int row, int g) -> bf16x8 {
    return *(const bf16x8*)(Lp + ((size_t)row << 7) + ((g ^ (row & 7)) << 4));
  };

#define QUAD(MB_, NB_, FB_)                                                     \
  do {                                                                          \
    __builtin_amdgcn_s_setprio(1);                                              \
    _Pragma("unroll") for (int m = 0; m < MH; ++m)                              \
      _Pragma("unroll") for (int n = 0; n < NH; ++n)                            \
        _Pragma("unroll") for (int kk = 0; kk < 2; ++kk)                        \
          acc[(MB_) + m][(NB_) + n] = __builtin_amdgcn_mfma_f32_16x16x32_bf16(  \
              fa[m][kk], FB_[n][kk], acc[(MB_) + m][(NB_) + n], 0, 0, 0);       \
    __builtin_amdgcn_s_setprio(0);                                              \
  } while (0)

  f32x4 acc[MREP][NREP] = {};
  bf16x8 fa[MH][2], fb0[NH][2], fb1[NH][2];
  const int nk = K >> 6;

  // prologue: tile0 fully (2*LL), tile1 half0 (LL); vmcnt(LL) retires tile0.
  stageA(0, 0, 0);
  stageB(0, 0, 0);
  stageA(0, 0, 1);
  stageB(0, 0, 1);
  stageA(1, 1, 0);
  stageB(1, 1, 0);
  vminf();
  BAR();

#pragma unroll 1
  for (int t = 0; t < nk; ++t) {
    const char* Lb = &lds[(t & 1) * STG];
    const int cur = t & 1, nbuf = cur ^ 1;
    const bool pf1 = (t + 1 < nk);
    // ---- phase 0: quadrant (0,0); stage A-half1 of t+1
#pragma unroll
    for (int m = 0; m < MH; ++m) {
      const int r = wm * (MREP * 16) + m * 16 + lr;
      fa[m][0] = LD(Lb, r, hi);
      fa[m][1] = LD(Lb, r, 4 + hi);
    }
#pragma unroll
    for (int n = 0; n < NH; ++n) {
      const int r = BM + wn * (NREP * 16) + n * 16 + lr;
      fb0[n][0] = LD(Lb, r, hi);
      fb0[n][1] = LD(Lb, r, 4 + hi);
    }
    if (pf1) stageA(nbuf, t + 1, 1);
    BAR();
    LGKM0();
    QUAD(0, 0, fb0);
    BAR();
    // ---- phase 1: quadrant (0,1); stage B-half1 of t+1
#pragma unroll
    for (int n = 0; n < NH; ++n) {
      const int r = BM + wn * (NREP * 16) + (NH + n) * 16 + lr;
      fb1[n][0] = LD(Lb, r, hi);
      fb1[n][1] = LD(Lb, r, 4 + hi);
    }
    if (pf1) stageB(nbuf, t + 1, 1);
    BAR();
    LGKM0();
    QUAD(0, NH, fb1);
    BAR();
    // ---- phase 2: quadrant (1,1); fa <- A half 1 (last reads of buf cur)
#pragma unroll
    for (int m = 0; m < MH; ++m) {
      const int r = wm * (MREP * 16) + (MH + m) * 16 + lr;
      fa[m][0] = LD(Lb, r, hi);
      fa[m][1] = LD(Lb, r, 4 + hi);
    }
    BAR();
    LGKM0();
    QUAD(MH, NH, fb1);
    BAR();
    // ---- phase 3: quadrant (1,0); stage t+2 half0 into cur; counted wait
    QUAD(MH, 0, fb0);
    if (t + 2 < nk) {
      stageA(cur, t + 2, 0);
      stageB(cur, t + 2, 0);
      vminf();  // all of t+1's 2*LL loads retired; t+2 half0 in flight
    } else {
      VM0();  // tail drain
    }
    BAR();
  }
#undef QUAD

  // =========================== fused epilogues ===========================
  if constexpr (EPI == 0) {
    bf16* cl = (bf16*)lds;
#pragma unroll
    for (int mi = 0; mi < MREP; ++mi)
#pragma unroll
      for (int ni = 0; ni < NREP; ++ni) {
        const int col = wn * (NREP * 16) + ni * 16 + lr;
        const float bv = biasf ? biasf[n0 + col] : 0.f;
#pragma unroll
        for (int j = 0; j < 4; ++j) {
          const int row = wm * (MREP * 16) + mi * 16 + (hi << 2) + j;
          cl[row * BN + ((((col >> 3) ^ (row & 7)) << 3) | (col & 7))] =
              (bf16)(acc[mi][ni][j] + bv);
        }
      }
    __syncthreads();
    constexpr int GPR = BN / 8;
    constexpr int PT = BM * GPR / THREADS;
#pragma unroll
    for (int c = 0; c < PT; ++c) {
      const int ch = c * THREADS + tid;
      const int row = ch / GPR, g = ch % GPR;
      bf16x8 vv = *(const bf16x8*)&cl[row * BN + ((g ^ (row & 7)) << 3)];
      *(bf16x8*)&((bf16*)C0)[(size_t)(m0 + row) * N + n0 + g * 8] = vv;
    }
  } else if constexpr (EPI == 1) {
    // V-transpose epilogue (BN == 128: tile spans exactly one head)
    bf16* cl = (bf16*)lds;
#pragma unroll
    for (int mi = 0; mi < MREP; ++mi)
#pragma unroll
      for (int ni = 0; ni < NREP; ++ni) {
        const int col = wn * (NREP * 16) + ni * 16 + lr;  // d
#pragma unroll
        for (int j = 0; j < 4; ++j) {
          const int row = wm * (MREP * 16) + mi * 16 + (hi << 2) + j;  // s-off
          cl[col * BM + ((((row >> 3) ^ (col & 7)) << 3) | (row & 7))] =
              (bf16)acc[mi][ni][j];
        }
      }
    __syncthreads();
    const int s0 = m0 & 1023, bq = m0 >> 10;
    bf16* vT = (bf16*)C0;
    const size_t vbase = (((size_t)(bq * 16 + (n0 >> 7)) * 128) << 10) + s0;
    constexpr int GPR = BM / 8;
    constexpr int PT = BN * GPR / THREADS;
#pragma unroll
    for (int c = 0; c < PT; ++c) {
      const int ch = c * THREADS + tid;
      const int d = ch / GPR, g = ch % GPR;
      bf16x8 vv = *(const bf16x8*)&cl[d * BM + ((g ^ (d & 7)) << 3)];
      *(bf16x8*)&vT[vbase + ((size_t)d << 10) + g * 8] = vv;
    }
  } else if constexpr (EPI == 2) {
    // RoPE epilogue (table-driven)
    bf16* cl = (bf16*)lds;
#pragma unroll
    for (int mi = 0; mi < MREP; ++mi)
#pragma unroll
      for (int ni = 0; ni < NREP; ++ni) {
        const int col = wn * (NREP * 16) + ni * 16 + lr;
#pragma unroll
        for (int j = 0; j < 4; ++j) {
          const int row = wm * (MREP * 16) + mi * 16 + (hi << 2) + j;
          cl[row * BN + ((((col >> 3) ^ (row & 7)) << 3) | (col & 7))] =
              (bf16)acc[mi][ni][j];
        }
      }
    __syncthreads();
    const int s0 = m0 & 1023, bq = m0 >> 10, head = n0 >> 8;
    bf16* qr = (bf16*)C0;
    bf16* kr = (bf16*)C1;
    const size_t qbase = ((size_t)((bq * 16 + head) * 1024 + s0) << 7);
    constexpr int GPR = BN / 8;
    constexpr int PT = BM * GPR / THREADS;
#pragma unroll
    for (int c = 0; c < PT; ++c) {
      const int ch = c * THREADS + tid;
      const int row = ch / GPR, g = ch % GPR;
      const int cc = g * 8;
      const int isk = cc >> 7, dd = cc & 127;
      bf16x8 vv = *(const bf16x8*)&cl[row * BN + ((g ^ (row & 7)) << 3)];
      bf16x8 out;
      if (dd < 64) {
        bf16x8 pp = *(const bf16x8*)&cl[row * BN + (((g ^ 4) ^ (row & 7)) << 3)];
        const f32x2* cp = &cst[(s0 + row) * 64 + dd];
#pragma unroll
        for (int e = 0; e < 8; ++e) {
          const f32x2 cs = cp[e];
          const float pv = (dd < 32) ? -(float)pp[e] : (float)pp[e];
          out[e] = (bf16)((float)vv[e] * cs[0] + pv * cs[1]);
        }
      } else {
        out = vv;
      }
      bf16* dst = isk ? kr : qr;
      *(bf16x8*)&dst[qbase + ((size_t)row << 7) + dd] = out;
    }
  } else {
    float* cl = (float*)lds;
#pragma unroll
    for (int mi = 0; mi < MREP; ++mi)
#pragma unroll
      for (int ni = 0; ni < NREP; ++ni) {
        const int col = wn * (NREP * 16) + ni * 16 + lr;
        const float bv = biasf ? biasf[n0 + col] : 0.f;
#pragma unroll
        for (int j = 0; j < 4; ++j) {
          const int row = wm * (MREP * 16) + mi * 16 + (hi << 2) + j;
          cl[row * BN + ((((col >> 2) ^ (row & 7)) << 2) | (col & 3))] =
              acc[mi][ni][j] + bv;
        }
      }
    __syncthreads();
    constexpr int GPR = BN / 4;
    constexpr int PT = BM * GPR / THREADS;
#pragma unroll
    for (int c = 0; c < PT; ++c) {
      const int ch = c * THREADS + tid;
      const int row = ch / GPR, g = ch % GPR;
      f32x4 vv = *(const f32x4*)&cl[row * BN + ((g ^ (row & 7)) << 2)];
      *(f32x4*)&((float*)C0)[(size_t)(m0 + row) * N + n0 + g * 4] = vv;
    }
  }
}

// ---------------------------------------------------------------------------
// 2-phase pipelined GEMM + LDS-staged epilogue — conv1.
// AMODE 2: dual-tap padded rows (logical K = 2*Kh). OUTPAD: write padded o1p.
// ---------------------------------------------------------------------------
template <int WM, int WN, int MREP, int NREP, int AMODE, bool OUTPAD>
__global__ __launch_bounds__(WM * WN * 64, 2) void gemm_pipe(
    const bf16* __restrict__ A, const bf16* __restrict__ W, void* __restrict__ Cout,
    const float* __restrict__ bias, int M, int N, int K) {
  constexpr int BM = WM * MREP * 16;
  constexpr int BN = WN * NREP * 16;
  constexpr int THREADS = WM * WN * 64;
  constexpr int ROWS = BM + BN;
  constexpr int CHA = BM * 4 / THREADS;
  constexpr int CHB = BN * 4 / THREADS;
  static_assert(CHA + CHB == 4, "vmcnt ledger assumes 4 loads/thread/stage");
  __shared__ bf16 lds[4][ROWS * 32];
  static_assert(BM * BN * 2 <= sizeof(lds), "C tile must fit LDS for epilogue");

  const int nbx = N / BN;
  const int nwg = (M / BM) * nbx;
  const int wgid = (blockIdx.x & 7) * (nwg >> 3) + (blockIdx.x >> 3);
  const int bx = wgid % nbx, by = wgid / nbx;
  const int m0 = by * BM, n0 = bx * BN;
  const int tid = threadIdx.x;
  const int w = tid >> 6, l = tid & 63;
  const int wm = w / WN, wn = w % WN;
  const int lr = l & 15;
  const int hi = l >> 4;

  auto aAddr = [&](int row, int t) -> const bf16* {
    const int m = m0 + row;
    if constexpr (AMODE == 2) {
      const int Kh2 = K >> 1, nkh = Kh2 >> 5;
      const int tap = (t >= nkh) ? 1 : 0;
      return A + (size_t)((m >> 10) * SP + (m & 1023) + tap) * Kh2 +
             ((t - (tap ? nkh : 0)) << 5);
    } else {
      return A + (size_t)m * K + (t << 5);
    }
  };

  auto stage = [&](int slot, int t) {
    const int k0 = t << 5;
#pragma unroll
    for (int c = 0; c < CHA; ++c) {
      const int ch = c * THREADS + tid;
      const int row = ch >> 2, cg = ch & 3;
      const int gc = (cg ^ ((row >> 1) & 3)) << 3;
      async16(aAddr(row, t) + gc, (char*)&lds[slot][0] + ch * 16);
    }
#pragma unroll
    for (int c = 0; c < CHB; ++c) {
      const int ch = c * THREADS + tid;
      const int row = ch >> 2, cg = ch & 3;
      const int gc = (cg ^ ((row >> 1) & 3)) << 3;
      async16(W + (size_t)(n0 + row) * K + k0 + gc,
              (char*)&lds[slot][0] + (BM * 4 + ch) * 16);
    }
  };

  f32x4 acc[MREP][NREP] = {};
  const int nk = K >> 5;

  stage(0, 0);
  stage(1, 1);
  stage(2, 2);
  asm volatile("s_waitcnt vmcnt(8)" ::: "memory");
  __builtin_amdgcn_s_barrier();
  __builtin_amdgcn_sched_barrier(0);

  bf16x8 fAc[MREP], fBc[NREP], fAn[MREP], fBn[NREP];
  {
    const char* nb = (const char*)&lds[0][0];
#pragma unroll
    for (int mi = 0; mi < MREP; ++mi) {
      const int r = wm * (MREP * 16) + mi * 16 + lr;
      fAc[mi] = *(const bf16x8*)(nb + r * 64 + ((hi ^ ((r >> 1) & 3)) << 4));
    }
#pragma unroll
    for (int ni = 0; ni < NREP; ++ni) {
      const int r = BM + wn * (NREP * 16) + ni * 16 + lr;
      fBc[ni] = *(const bf16x8*)(nb + r * 64 + ((hi ^ ((r >> 1) & 3)) << 4));
    }
  }

#define GSTEP(T_, CA, CB, NA, NB)                                              \
  do {                                                                         \
    if ((T_) + 2 < nk) asm volatile("s_waitcnt vmcnt(4)" ::: "memory");        \
    else               asm volatile("s_waitcnt vmcnt(0)" ::: "memory");        \
    __builtin_amdgcn_s_barrier();                                              \
    __builtin_amdgcn_sched_barrier(0);                                         \
    if ((T_) + 3 < nk) stage(((T_) + 3) & 3, (T_) + 3);                        \
    if ((T_) + 1 < nk) {                                                       \
      const char* nb = (const char*)&lds[((T_) + 1) & 3][0];                   \
      _Pragma("unroll") for (int mi = 0; mi < MREP; ++mi) {                    \
        const int r = wm * (MREP * 16) + mi * 16 + lr;                         \
        NA[mi] = *(const bf16x8*)(nb + r * 64 + ((hi ^ ((r >> 1) & 3)) << 4)); \
      }                                                                        \
      _Pragma("unroll") for (int ni = 0; ni < NREP; ++ni) {                    \
        const int r = BM + wn * (NREP * 16) + ni * 16 + lr;                    \
        NB[ni] = *(const bf16x8*)(nb + r * 64 + ((hi ^ ((r >> 1) & 3)) << 4)); \
      }                                                                        \
    }                                                                          \
    __builtin_amdgcn_s_setprio(1);                                             \
    _Pragma("unroll") for (int mi = 0; mi < MREP; ++mi)                        \
      _Pragma("unroll") for (int ni = 0; ni < NREP; ++ni)                      \
        acc[mi][ni] =                                                          \
            __builtin_amdgcn_mfma_f32_16x16x32_bf16(CA[mi], CB[ni], acc[mi][ni], 0, 0, 0); \
    __builtin_amdgcn_s_setprio(0);                                             \
  } while (0)

  for (int t = 0; t < nk; t += 2) {
    GSTEP(t, fAc, fBc, fAn, fBn);
    GSTEP(t + 1, fAn, fBn, fAc, fBc);
  }
#undef GSTEP

  // ---- LDS-staged coalesced epilogue (bf16, optionally padded rows) ----
  __syncthreads();
  {
    bf16* cl = (bf16*)&lds[0][0];
#pragma unroll
    for (int mi = 0; mi < MREP; ++mi) {
#pragma unroll
      for (int ni = 0; ni < NREP; ++ni) {
        const int col = wn * (NREP * 16) + ni * 16 + lr;
        const float bv = bias ? bias[n0 + col] : 0.f;
#pragma unroll
        for (int j = 0; j < 4; ++j) {
          const int row = wm * (MREP * 16) + mi * 16 + (hi << 2) + j;
          cl[row * BN + ((((col >> 3) ^ (row & 7)) << 3) | (col & 7))] =
              (bf16)(acc[mi][ni][j] + bv);
        }
      }
    }
    __syncthreads();
    constexpr int GPR = BN / 8;
    constexpr int PT = BM * GPR / THREADS;
#pragma unroll
    for (int c = 0; c < PT; ++c) {
      const int ch = c * THREADS + tid;
      const int row = ch / GPR, g = ch % GPR;
      const int mr = m0 + row;
      const size_t orow = OUTPAD ? (size_t)((mr >> 10) * SP + (mr & 1023) + 1)
                                 : (size_t)mr;
      bf16x8 vv = *(const bf16x8*)&cl[row * BN + ((g ^ (row & 7)) << 3)];
      *(bf16x8*)&((bf16*)Cout)[orow * N + n0 + g * 8] = vv;
    }
  }
}

// ---------------------------------------------------------------------------
// fp32 -> bf16 weight conversion (vectorized by 4) — Wo only
// ---------------------------------------------------------------------------
__global__ void k_f2b4(const float* __restrict__ in, bf16* __restrict__ out, int n4) {
  int i = blockIdx.x * 256 + threadIdx.x;
  if (i >= n4) return;
  float4 v = ((const float4*)in)[i];
  bf16x4 o = {(bf16)v.x, (bf16)v.y, (bf16)v.z, (bf16)v.w};
  ((bf16x4*)out)[i] = o;
}

// ---------------------------------------------------------------------------
// k_prep: ONE kernel for all input prep (R15 glue consolidation):
//   - padded hsbp (B,S+1,H): row 0 = lf1, rows 1..S = bf16(hid)
//   - o1p row-0 prefill = lf2; trig table cst
//   - weight conversions (segmented per-thread tasks, 5.24M items):
//       [0,2.10M)   Wqk f2b x4      -> WqkB (ws Wslot)
//       [2.10,3.15) Wv  f2b x4      -> WvB  (d_out scratch)
//       [3.15,4.19) c1w deint       -> W1d  (d_out scratch +8MB)
//       [4.19,5.24) c2w deint       -> W2d  (d_out scratch +16MB)
//   d_out-as-scratch is legal: fully overwritten by the final GEMM each call.
// ---------------------------------------------------------------------------
__global__ void k_prep(const float* __restrict__ hid, const float* __restrict__ lf1,
                       const float* __restrict__ lf2, const float* __restrict__ rot,
                       const float* __restrict__ Wqk, const float* __restrict__ Wv,
                       const float* __restrict__ c1w, const float* __restrict__ c2w,
                       bf16* __restrict__ hsbp, bf16* __restrict__ o1p,
                       f32x2* __restrict__ cst, bf16* __restrict__ WqkB,
                       bf16* __restrict__ WvB, bf16* __restrict__ W1d,
                       bf16* __restrict__ W2d) {
  int idx = blockIdx.x * 256 + threadIdx.x;  // < T*H = 8.4M
  // --- hsbp build ---
  {
    int t = idx >> 11, h = idx & 2047;
    int b = t >> 10, s = t & 1023;
    hsbp[((size_t)(b * SP + s + 1) << 11) + h] = (bf16)hid[idx];
    if (idx < Bc * Hc) {
      int bb = idx >> 11, hh = idx & 2047;
      hsbp[((size_t)(bb * SP) << 11) + hh] = (bf16)lf1[idx];
    }
    if (idx < Bc * 1024) {
      int bb = idx >> 10, cc = idx & 1023;
      o1p[((size_t)(bb * SP) << 10) + cc] = (bf16)lf2[idx];
    }
    if (idx < Sc * 64) {
      float f = rot[idx];
      f32x2 cs = {cosf(f), sinf(f)};
      cst[idx] = cs;
    }
  }
  // --- weight conversions (segments) ---
  if (idx < 2097152) {                     // Wqk: 8.4M f32, x4
    float4 v = ((const float4*)Wqk)[idx];
    bf16x4 o = {(bf16)v.x, (bf16)v.y, (bf16)v.z, (bf16)v.w};
    ((bf16x4*)WqkB)[idx] = o;
  } else if (idx < 3145728) {              // Wv: 4.2M f32, x4
    int j = idx - 2097152;
    float4 v = ((const float4*)Wv)[j];
    bf16x4 o = {(bf16)v.x, (bf16)v.y, (bf16)v.z, (bf16)v.w};
    ((bf16x4*)WvB)[j] = o;
  } else if (idx < 4194304) {              // c1w deint: O=1024, Hd=2048
    int j = idx - 3145728;                 // j < 1024*1024
    int o = j >> 10, h0 = (j & 1023) * 2;
    float4 v = *(const float4*)&c1w[(size_t)o * 4096 + h0 * 2];
    bf16x2 t0 = {(bf16)v.x, (bf16)v.z};
    bf16x2 t1 = {(bf16)v.y, (bf16)v.w};
    *(bf16x2*)&W1d[(size_t)o * 4096 + h0] = t0;
    *(bf16x2*)&W1d[(size_t)o * 4096 + 2048 + h0] = t1;
  } else if (idx < 5242880) {              // c2w deint: O=2048, Hd=1024
    int j = idx - 4194304;                 // j < 2048*512
    int o = j >> 9, h0 = (j & 511) * 2;
    float4 v = *(const float4*)&c2w[(size_t)o * 2048 + h0 * 2];
    bf16x2 t0 = {(bf16)v.x, (bf16)v.z};
    bf16x2 t1 = {(bf16)v.y, (bf16)v.w};
    *(bf16x2*)&W2d[(size_t)o * 2048 + h0] = t0;
    *(bf16x2*)&W2d[(size_t)o * 2048 + 1024 + h0] = t1;
  }
}

// lf = rmsnorm(o2 + hid) * g   (one block per row, 256 thr x 8 elems)
__global__ __launch_bounds__(256) void k_rmsnorm(const bf16* __restrict__ o2,
                                                 const float* __restrict__ hid,
                                                 const float* __restrict__ g,
                                                 bf16* __restrict__ lf) {
  int t = blockIdx.x, tid = threadIdx.x;
  size_t base = ((size_t)t << 11) + tid * 8;
  bf16x8 ov = *(const bf16x8*)&o2[base];
  const float* hp = &hid[base];
  float vals[8];
  float ss = 0.f;
#pragma unroll
  for (int i = 0; i < 8; ++i) {
    float x = (float)ov[i] + hp[i];
    vals[i] = x;
    ss += x * x;
  }
#pragma unroll
  for (int off = 1; off < 64; off <<= 1) ss += __shfl_xor(ss, off);
  __shared__ float red[4];
  if ((tid & 63) == 0) red[tid >> 6] = ss;
  __syncthreads();
  float tot = red[0] + red[1] + red[2] + red[3];
  float inv = rsqrtf(tot * (1.f / 2048.f) + 1e-6f);
  bf16x8 o;
#pragma unroll
  for (int i = 0; i < 8; ++i) o[i] = (bf16)(vals[i] * inv * g[tid * 8 + i]);
  *(bf16x8*)&lf[base] = o;
}

// ---------------------------------------------------------------------------
// causal flash attention v3: LDS-staged K/V (dbuf), balanced q-tile pairs,
// XCD-local (b,h) mapping, setprio around MFMA clusters, defer-max (THR=8).
// ---------------------------------------------------------------------------
__global__ __launch_bounds__(256, 2) void k_attn(const bf16* __restrict__ qr,
                                                 const bf16* __restrict__ kr,
                                                 const bf16* __restrict__ vT,
                                                 bf16* __restrict__ att) {
  __shared__ bf16 Ks[2][64 * 128];
  __shared__ bf16 Vs[2][128 * 64];
  __shared__ bf16 plds[4][16 * 64];
  const int bid = blockIdx.x;
  const int xcd = bid & 7, jj = bid >> 3;
  const int bn = xcd * 8 + (jj >> 3);
  const int pr = jj & 7;
  const int tid = threadIdx.x, w = tid >> 6, l = tid & 63;
  const int lr = l & 15, hi = l >> 4;
  const bf16* kb = kr + ((size_t)bn << 17);
  const bf16* vb = vT + ((size_t)bn << 17);
  const int b = bn >> 4, hh = bn & 15;
  const float scaling = 0.08838834764831845f;
  const float THR = 8.f;

  auto stage = [&](int buf, int kt) {
#pragma unroll
    for (int c = 0; c < 4; ++c) {
      int chunk = c * 256 + tid;
      int prow = chunk >> 4, pcg = chunk & 15;
      async16(kb + ((size_t)(kt * 64 + prow) << 7) + ((pcg ^ (prow & 7)) << 3),
              (char*)&Ks[buf][0] + chunk * 16);
    }
#pragma unroll
    for (int c = 0; c < 4; ++c) {
      int chunk = c * 256 + tid;
      int prow = chunk >> 3, pcg = chunk & 7;
      async16(vb + ((size_t)prow << 10) + kt * 64 + ((pcg ^ (prow & 7)) << 3),
              (char*)&Vs[buf][0] + chunk * 16);
    }
  };

#pragma unroll 1
  for (int phase = 0; phase < 2; ++phase) {
    const int qt = phase ? (15 - pr) : pr;
    const int qg0 = qt * 64 + w * 16;
    const bf16* qb = qr + ((size_t)(bn * 1024 + qg0) << 7);
    bf16x8 qf[4];
#pragma unroll
    for (int ks = 0; ks < 4; ++ks) qf[ks] = *(const bf16x8*)&qb[lr * 128 + ks * 32 + hi * 8];
    f32x4 oacc[8] = {};
    float mrow[4] = {-1e30f, -1e30f, -1e30f, -1e30f};
    float lrow[4] = {0.f, 0.f, 0.f, 0.f};
    const int nkb = qt + 1;

    stage(0, 0);
    __syncthreads();

    for (int kbt = 0; kbt < nkb; ++kbt) {
      const int cur = kbt & 1;
      if (kbt + 1 < nkb) stage(cur ^ 1, kbt + 1);

      f32x4 sacc[4] = {};
      __builtin_amdgcn_s_setprio(1);
#pragma unroll
      for (int n = 0; n < 4; ++n) {
        const int krow = n * 16 + lr;
#pragma unroll
        for (int ks = 0; ks < 4; ++ks) {
          bf16x8 kf = *(const bf16x8*)&Ks[cur][(krow << 7) + ((((ks << 2) | hi) ^ (krow & 7)) << 3)];
          sacc[n] = __builtin_amdgcn_mfma_f32_16x16x32_bf16(qf[ks], kf, sacc[n], 0, 0, 0);
        }
      }
      __builtin_amdgcn_s_setprio(0);
      const bool needmask = (kbt * 64 + 63 > qg0);
#pragma unroll
      for (int n = 0; n < 4; ++n) {
        int kg = kbt * 64 + n * 16 + lr;
#pragma unroll
        for (int j = 0; j < 4; ++j) {
          float sv = sacc[n][j] * scaling;
          if (needmask && kg > qg0 + hi * 4 + j) sv = -1e30f;
          sacc[n][j] = sv;
        }
      }
      float pm[4];
#pragma unroll
      for (int j = 0; j < 4; ++j) {
        float p = fmaxf(fmaxf(sacc[0][j], sacc[1][j]), fmaxf(sacc[2][j], sacc[3][j]));
        p = fmaxf(p, __shfl_xor(p, 1));
        p = fmaxf(p, __shfl_xor(p, 2));
        p = fmaxf(p, __shfl_xor(p, 4));
        p = fmaxf(p, __shfl_xor(p, 8));
        pm[j] = p;
      }
      float sf[4] = {1.f, 1.f, 1.f, 1.f};
      bool needup = (pm[0] > mrow[0] + THR) || (pm[1] > mrow[1] + THR) ||
                    (pm[2] > mrow[2] + THR) || (pm[3] > mrow[3] + THR);
      if (__any(needup)) {
#pragma unroll
        for (int j = 0; j < 4; ++j) {
          float mn = fmaxf(mrow[j], pm[j]);
          sf[j] = __expf(mrow[j] - mn);
          mrow[j] = mn;
        }
#pragma unroll
        for (int dt = 0; dt < 8; ++dt)
#pragma unroll
          for (int j = 0; j < 4; ++j) oacc[dt][j] *= sf[j];
      }
#pragma unroll
      for (int n = 0; n < 4; ++n)
#pragma unroll
        for (int j = 0; j < 4; ++j) sacc[n][j] = __expf(sacc[n][j] - mrow[j]);
#pragma unroll
      for (int j = 0; j < 4; ++j) {
        float ps = sacc[0][j] + sacc[1][j] + sacc[2][j] + sacc[3][j];
        ps += __shfl_xor(ps, 1);
        ps += __shfl_xor(ps, 2);
        ps += __shfl_xor(ps, 4);
        ps += __shfl_xor(ps, 8);
        lrow[j] = lrow[j] * sf[j] + ps;
      }
#pragma unroll
      for (int n = 0; n < 4; ++n)
#pragma unroll
        for (int j = 0; j < 4; ++j)
          plds[w][(hi * 4 + j) * 64 + n * 16 + lr] = (bf16)sacc[n][j];
      asm volatile("s_waitcnt lgkmcnt(0)" ::: "memory");
      __builtin_amdgcn_s_setprio(1);
#pragma unroll
      for (int ks2 = 0; ks2 < 2; ++ks2) {
        bf16x8 pf = *(const bf16x8*)&plds[w][lr * 64 + ks2 * 32 + hi * 8];
#pragma unroll
        for (int dt = 0; dt < 8; ++dt) {
          const int vrow = dt * 16 + lr;
          bf16x8 vf = *(const bf16x8*)&Vs[cur][(vrow << 6) + ((((ks2 << 2) | hi) ^ (lr & 7)) << 3)];
          oacc[dt] = __builtin_amdgcn_mfma_f32_16x16x32_bf16(pf, vf, oacc[dt], 0, 0, 0);
        }
      }
      __builtin_amdgcn_s_setprio(0);
      __syncthreads();
    }

#pragma unroll
    for (int j = 0; j < 4; ++j) {
      float inv = 1.f / lrow[j];
      int qg = qg0 + hi * 4 + j;
      size_t obase = ((size_t)(b * 1024 + qg) << 11) + hh * 128;
#pragma unroll
      for (int dt = 0; dt < 8; ++dt) att[obase + dt * 16 + lr] = (bf16)(oacc[dt][j] * inv);
    }
  }
}

// ---------------------------------------------------------------------------
// Workspace plan (~124 MB ws + d_out scratch):
//   ws  0-16   WqkB -> (after Wqk gemm) WoB
//   ws 16-34   hsbp [dead after conv1] -> att
//   ws 34-43   o1p  [dead after conv2]
//   ws 43-59   o2 | 59-75 lfb | 75-91 vT | 91-107 qr | 107-123 kr | 123 cst
//   d_out 0-8  WvB | 8-16 W1d | 16-24 W2d   (scratch; final GEMM overwrites)
// ---------------------------------------------------------------------------
extern "C" void kernel_launch(void* const* d_in, const int* in_sizes, int n_in,
                              void* d_out, int out_size, void* d_ws, size_t ws_size,
                              hipStream_t stream) {
  const float* hid = (const float*)d_in[1];
  const float* rot = (const float*)d_in[2];
  const float* lf1 = (const float*)d_in[3];
  const float* lf2 = (const float*)d_in[4];
  const float* Wqk = (const float*)d_in[5];
  const float* Wv  = (const float*)d_in[6];
  const float* Wo  = (const float*)d_in[7];
  const float* c1w = (const float*)d_in[8];
  const float* c2w = (const float*)d_in[10];
  const float* c1b = (const float*)d_in[9];
  const float* c2b = (const float*)d_in[11];
  const float* lng = (const float*)d_in[12];
  float* outp = (float*)d_out;
  char* ws = (char*)d_ws;
  char* od = (char*)d_out;

  const size_t MB = 1ull << 20;
  bf16* Wslot = (bf16*)(ws + 0 * MB);    // WqkB, then WoB
  bf16* hsbp  = (bf16*)(ws + 16 * MB);
  bf16* att   = (bf16*)(ws + 16 * MB);   // alias (hsbp dead after conv1)
  bf16* o1p   = (bf16*)(ws + 34 * MB);
  bf16* o2    = (bf16*)(ws + 43 * MB);
  bf16* lfb   = (bf16*)(ws + 59 * MB);
  bf16* vT    = (bf16*)(ws + 75 * MB);
  bf16* qr    = (bf16*)(ws + 91 * MB);
  bf16* kr    = (bf16*)(ws + 107 * MB);
  f32x2* cst  = (f32x2*)(ws + 123 * MB);
  // d_out scratch (fully overwritten by final GEMM each call)
  bf16* WvB   = (bf16*)(od + 0 * MB);    // 8 MB
  bf16* W1d   = (bf16*)(od + 8 * MB);    // 8 MB
  bf16* W2d   = (bf16*)(od + 16 * MB);   // 8 MB

  // 0. ONE prep kernel: padded inputs + trig + 4 weight conversions
  k_prep<<<Tc * Hc / 256, 256, 0, stream>>>(hid, lf1, lf2, rot, Wqk, Wv, c1w, c2w,
                                            hsbp, o1p, cst, Wslot, WvB, W1d, W2d);

  // 1. v = hs @ Wv.T (padded rows), fused V-transpose -> vT (128^2, 2/CU)
  gemm8<2, 2, 4, 4, 1, 1><<<512, 256, 0, stream>>>(hsbp, WvB, vT, nullptr, nullptr,
                                                   nullptr, Tc, Pc, Hc);

  // 2. conv1: dual-tap GEMM (logical K=4096 over hsbp taps) -> padded o1p
  gemm_pipe<2, 2, 4, 4, 2, true><<<256, 256, 0, stream>>>(hsbp, W1d, o1p, c1b,
                                                          Tc, 1024, 4096);

  // 3. conv2: dual-tap GEMM (logical K=2048 over o1p taps) -> o2 (128^2)
  gemm8<2, 2, 4, 4, 0, 2><<<512, 256, 0, stream>>>(o1p, W2d, o2, nullptr, c2b,
                                                   nullptr, Tc, 2048, 2048);

  // 4. residual + rmsnorm
  k_rmsnorm<<<Tc, 256, 0, stream>>>(o2, hid, lng, lfb);

  // 5. qk projection (256^2, 512 thr), fused RoPE epilogue -> qr, kr
  gemm8<2, 4, 8, 4, 2, 0><<<256, 512, 0, stream>>>(lfb, Wslot, qr, kr, nullptr, cst,
                                                   Tc, 4096, Hc);

  // 6. Wo conversion (Wslot free now) + attention
  k_f2b4<<<(2048 * 2048 / 4 + 255) / 256, 256, 0, stream>>>(Wo, Wslot, 2048 * 2048 / 4);
  k_attn<<<Bc * NHc * 8, 256, 0, stream>>>(qr, kr, vT, att);

  // 7. output projection (fp32 out; overwrites d_out scratch; 128^2)
  gemm8<2, 2, 4, 4, 3, 0><<<512, 256, 0, stream>>>(att, Wslot, outp, nullptr, nullptr,
                                                   nullptr, Tc, 2048, 2048);
}

// Round 17
// 334.027 us; speedup vs baseline: 1.0407x; 1.0016x over previous
//
#include <hip/hip_runtime.h>

typedef __bf16 bf16;
typedef __bf16 bf16x8 __attribute__((ext_vector_type(8)));
typedef __bf16 bf16x4 __attribute__((ext_vector_type(4)));
typedef __bf16 bf16x2 __attribute__((ext_vector_type(2)));
typedef float f32x4 __attribute__((ext_vector_type(4)));
typedef float f32x2 __attribute__((ext_vector_type(2)));

#define DEVI __device__ __forceinline__

// problem constants
constexpr int Bc = 4, Sc = 1024, Hc = 2048, NHc = 16, HDc = 128;
constexpr int Tc = Bc * Sc;   // 4096
constexpr int Pc = NHc * HDc; // 2048
constexpr int SP = Sc + 1;    // padded tokens per batch (row 0 = cache)

DEVI void async16(const void* g, void* l) {
  __builtin_amdgcn_global_load_lds(
      (const __attribute__((address_space(1))) unsigned int*)g,
      (__attribute__((address_space(3))) unsigned int*)l, 16, 0, 0);
}

#define BAR() __builtin_amdgcn_s_barrier()
#define LGKM0()                                          \
  do {                                                   \
    asm volatile("s_waitcnt lgkmcnt(0)" ::: "memory");   \
    __builtin_amdgcn_sched_barrier(0);                   \
  } while (0)
#define VM0() asm volatile("s_waitcnt vmcnt(0)" ::: "memory")

// ---------------------------------------------------------------------------
// 8-phase GEMM, counted-vmcnt cross-tile pipeline (R12-verified ledger),
// templatized by THREADS = WM*WN*64.
// AMODE: 0 dense | 1 padded-token rows | 2 conv dual-tap (logical K=2*Kh).
// EPI: 0 bf16+bias | 1 V-transpose->vT | 2 RoPE(table)->qr,kr | 3 f32.
// ---------------------------------------------------------------------------
template <int WM, int WN, int MREP, int NREP, int EPI, int AMODE>
__global__ __launch_bounds__(WM * WN * 64, 2) void gemm8(
    const bf16* __restrict__ A, const bf16* __restrict__ W,
    void* __restrict__ C0, void* __restrict__ C1,
    const float* __restrict__ biasf, const f32x2* __restrict__ cst,
    int M, int N, int K) {
  constexpr int THREADS = WM * WN * 64;
  constexpr int BM = WM * MREP * 16;
  constexpr int BN = WN * NREP * 16;
  constexpr int MH = MREP / 2, NH = NREP / 2;
  constexpr int LA = BM * 4 / THREADS;   // per-thread loads per A half-tile
  constexpr int LB = BN * 4 / THREADS;
  constexpr int STG = (BM + BN) * 128;   // staging buffer bytes
  constexpr int OUTB = (EPI == 3) ? 4 : 2;
  constexpr int CBYTES = BM * BN * OUTB;
  constexpr int LDSB = (2 * STG > CBYTES) ? 2 * STG : CBYTES;
  __shared__ char lds[LDSB];

  const int nbx = N / BN;
  const int nwg = (M / BM) * nbx;
  int bx, by;
  if (nwg == 256 && nbx == 16) {
    const int xcd = blockIdx.x & 7, loc = blockIdx.x >> 3;
    by = (xcd >> 1) * 4 + (loc >> 3);
    bx = (xcd & 1) * 8 + (loc & 7);
  } else {
    const int wgid = (blockIdx.x & 7) * (nwg >> 3) + (blockIdx.x >> 3);
    bx = wgid % nbx;
    by = wgid / nbx;
  }
  const int m0 = by * BM, n0 = bx * BN;
  const int tid = threadIdx.x;
  const int w = tid >> 6, l = tid & 63;
  const int wm = w / WN, wn = w % WN;
  const int lr = l & 15, hi = l >> 4;

  // counted wait: leave exactly one half-tile (LL loads) in flight
  auto vminf = [&] {
    constexpr int LL = LA + LB;
    if constexpr (LL == 4)      asm volatile("s_waitcnt vmcnt(4)" ::: "memory");
    else if constexpr (LL == 3) asm volatile("s_waitcnt vmcnt(3)" ::: "memory");
    else if constexpr (LL == 2) asm volatile("s_waitcnt vmcnt(2)" ::: "memory");
    else                        asm volatile("s_waitcnt vmcnt(0)" ::: "memory");
  };

  auto aAddr = [&](int row, int t) -> const bf16* {
    const int m = m0 + row;
    if constexpr (AMODE == 0) {
      return A + (size_t)m * K + (t << 6);
    } else if constexpr (AMODE == 1) {
      return A + (size_t)((m >> 10) * SP + (m & 1023) + 1) * K + (t << 6);
    } else {
      const int Kh2 = K >> 1, nkh = Kh2 >> 6;
      const int tap = (t >= nkh) ? 1 : 0;
      return A + (size_t)((m >> 10) * SP + (m & 1023) + tap) * Kh2 +
             ((t - (tap ? nkh : 0)) << 6);
    }
  };

  auto stageA = [&](int buf, int t, int half) {
#pragma unroll
    for (int c = 0; c < LA; ++c) {
      const int ch = c * THREADS + tid;
      const int row = half * (BM / 2) + (ch >> 3);
      const int grp = ch & 7;
      async16(aAddr(row, t) + ((grp ^ (row & 7)) << 3),
              &lds[buf * STG + row * 128 + grp * 16]);
    }
  };
  auto stageB = [&](int buf, int t, int half) {
#pragma unroll
    for (int c = 0; c < LB; ++c) {
      const int ch = c * THREADS + tid;
      const int row = half * (BN / 2) + (ch >> 3);
      const int grp = ch & 7;
      async16(W + (size_t)(n0 + row) * K + (t << 6) + ((grp ^ (row & 7)) << 3),
              &lds[buf * STG + BM * 128 + row * 128 + grp * 16]);
    }
  };
  auto LD = [&](const char* Lp, int row, int g) -> bf16x8 {
    return *(const bf16x8*)(Lp + ((size_t)row << 7) + ((g ^ (row & 7)) << 4));
  };

#define QUAD(MB_, NB_, FB_)                                                     \
  do {                                                                          \
    __builtin_amdgcn_s_setprio(1);                                              \
    _Pragma("unroll") for (int m = 0; m < MH; ++m)                              \
      _Pragma("unroll") for (int n = 0; n < NH; ++n)                            \
        _Pragma("unroll") for (int kk = 0; kk < 2; ++kk)                        \
          acc[(MB_) + m][(NB_) + n] = __builtin_amdgcn_mfma_f32_16x16x32_bf16(  \
              fa[m][kk], FB_[n][kk], acc[(MB_) + m][(NB_) + n], 0, 0, 0);       \
    __builtin_amdgcn_s_setprio(0);                                              \
  } while (0)

  f32x4 acc[MREP][NREP] = {};
  bf16x8 fa[MH][2], fb0[NH][2], fb1[NH][2];
  const int nk = K >> 6;

  // prologue: tile0 fully (2*LL), tile1 half0 (LL); vmcnt(LL) retires tile0.
  stageA(0, 0, 0);
  stageB(0, 0, 0);
  stageA(0, 0, 1);
  stageB(0, 0, 1);
  stageA(1, 1, 0);
  stageB(1, 1, 0);
  vminf();
  BAR();

#pragma unroll 1
  for (int t = 0; t < nk; ++t) {
    const char* Lb = &lds[(t & 1) * STG];
    const int cur = t & 1, nbuf = cur ^ 1;
    const bool pf1 = (t + 1 < nk);
    // ---- phase 0: quadrant (0,0); stage A-half1 of t+1
#pragma unroll
    for (int m = 0; m < MH; ++m) {
      const int r = wm * (MREP * 16) + m * 16 + lr;
      fa[m][0] = LD(Lb, r, hi);
      fa[m][1] = LD(Lb, r, 4 + hi);
    }
#pragma unroll
    for (int n = 0; n < NH; ++n) {
      const int r = BM + wn * (NREP * 16) + n * 16 + lr;
      fb0[n][0] = LD(Lb, r, hi);
      fb0[n][1] = LD(Lb, r, 4 + hi);
    }
    if (pf1) stageA(nbuf, t + 1, 1);
    BAR();
    LGKM0();
    QUAD(0, 0, fb0);
    BAR();
    // ---- phase 1: quadrant (0,1); stage B-half1 of t+1
#pragma unroll
    for (int n = 0; n < NH; ++n) {
      const int r = BM + wn * (NREP * 16) + (NH + n) * 16 + lr;
      fb1[n][0] = LD(Lb, r, hi);
      fb1[n][1] = LD(Lb, r, 4 + hi);
    }
    if (pf1) stageB(nbuf, t + 1, 1);
    BAR();
    LGKM0();
    QUAD(0, NH, fb1);
    BAR();
    // ---- phase 2: quadrant (1,1); fa <- A half 1 (last reads of buf cur)
#pragma unroll
    for (int m = 0; m < MH; ++m) {
      const int r = wm * (MREP * 16) + (MH + m) * 16 + lr;
      fa[m][0] = LD(Lb, r, hi);
      fa[m][1] = LD(Lb, r, 4 + hi);
    }
    BAR();
    LGKM0();
    QUAD(MH, NH, fb1);
    BAR();
    // ---- phase 3: quadrant (1,0); stage t+2 half0 into cur; counted wait
    QUAD(MH, 0, fb0);
    if (t + 2 < nk) {
      stageA(cur, t + 2, 0);
      stageB(cur, t + 2, 0);
      vminf();  // all of t+1's 2*LL loads retired; t+2 half0 in flight
    } else {
      VM0();  // tail drain
    }
    BAR();
  }
#undef QUAD

  // =========================== fused epilogues ===========================
  if constexpr (EPI == 0) {
    bf16* cl = (bf16*)lds;
#pragma unroll
    for (int mi = 0; mi < MREP; ++mi)
#pragma unroll
      for (int ni = 0; ni < NREP; ++ni) {
        const int col = wn * (NREP * 16) + ni * 16 + lr;
        const float bv = biasf ? biasf[n0 + col] : 0.f;
#pragma unroll
        for (int j = 0; j < 4; ++j) {
          const int row = wm * (MREP * 16) + mi * 16 + (hi << 2) + j;
          cl[row * BN + ((((col >> 3) ^ (row & 7)) << 3) | (col & 7))] =
              (bf16)(acc[mi][ni][j] + bv);
        }
      }
    __syncthreads();
    constexpr int GPR = BN / 8;
    constexpr int PT = BM * GPR / THREADS;
#pragma unroll
    for (int c = 0; c < PT; ++c) {
      const int ch = c * THREADS + tid;
      const int row = ch / GPR, g = ch % GPR;
      bf16x8 vv = *(const bf16x8*)&cl[row * BN + ((g ^ (row & 7)) << 3)];
      *(bf16x8*)&((bf16*)C0)[(size_t)(m0 + row) * N + n0 + g * 8] = vv;
    }
  } else if constexpr (EPI == 1) {
    // V-transpose epilogue (BN == 128: tile spans exactly one head)
    bf16* cl = (bf16*)lds;
#pragma unroll
    for (int mi = 0; mi < MREP; ++mi)
#pragma unroll
      for (int ni = 0; ni < NREP; ++ni) {
        const int col = wn * (NREP * 16) + ni * 16 + lr;  // d
#pragma unroll
        for (int j = 0; j < 4; ++j) {
          const int row = wm * (MREP * 16) + mi * 16 + (hi << 2) + j;  // s-off
          cl[col * BM + ((((row >> 3) ^ (col & 7)) << 3) | (row & 7))] =
              (bf16)acc[mi][ni][j];
        }
      }
    __syncthreads();
    const int s0 = m0 & 1023, bq = m0 >> 10;
    bf16* vT = (bf16*)C0;
    const size_t vbase = (((size_t)(bq * 16 + (n0 >> 7)) * 128) << 10) + s0;
    constexpr int GPR = BM / 8;
    constexpr int PT = BN * GPR / THREADS;
#pragma unroll
    for (int c = 0; c < PT; ++c) {
      const int ch = c * THREADS + tid;
      const int d = ch / GPR, g = ch % GPR;
      bf16x8 vv = *(const bf16x8*)&cl[d * BM + ((g ^ (d & 7)) << 3)];
      *(bf16x8*)&vT[vbase + ((size_t)d << 10) + g * 8] = vv;
    }
  } else if constexpr (EPI == 2) {
    // RoPE epilogue (table-driven)
    bf16* cl = (bf16*)lds;
#pragma unroll
    for (int mi = 0; mi < MREP; ++mi)
#pragma unroll
      for (int ni = 0; ni < NREP; ++ni) {
        const int col = wn * (NREP * 16) + ni * 16 + lr;
#pragma unroll
        for (int j = 0; j < 4; ++j) {
          const int row = wm * (MREP * 16) + mi * 16 + (hi << 2) + j;
          cl[row * BN + ((((col >> 3) ^ (row & 7)) << 3) | (col & 7))] =
              (bf16)acc[mi][ni][j];
        }
      }
    __syncthreads();
    const int s0 = m0 & 1023, bq = m0 >> 10, head = n0 >> 8;
    bf16* qr = (bf16*)C0;
    bf16* kr = (bf16*)C1;
    const size_t qbase = ((size_t)((bq * 16 + head) * 1024 + s0) << 7);
    constexpr int GPR = BN / 8;
    constexpr int PT = BM * GPR / THREADS;
#pragma unroll
    for (int c = 0; c < PT; ++c) {
      const int ch = c * THREADS + tid;
      const int row = ch / GPR, g = ch % GPR;
      const int cc = g * 8;
      const int isk = cc >> 7, dd = cc & 127;
      bf16x8 vv = *(const bf16x8*)&cl[row * BN + ((g ^ (row & 7)) << 3)];
      bf16x8 out;
      if (dd < 64) {
        bf16x8 pp = *(const bf16x8*)&cl[row * BN + (((g ^ 4) ^ (row & 7)) << 3)];
        const f32x2* cp = &cst[(s0 + row) * 64 + dd];
#pragma unroll
        for (int e = 0; e < 8; ++e) {
          const f32x2 cs = cp[e];
          const float pv = (dd < 32) ? -(float)pp[e] : (float)pp[e];
          out[e] = (bf16)((float)vv[e] * cs[0] + pv * cs[1]);
        }
      } else {
        out = vv;
      }
      bf16* dst = isk ? kr : qr;
      *(bf16x8*)&dst[qbase + ((size_t)row << 7) + dd] = out;
    }
  } else {
    float* cl = (float*)lds;
#pragma unroll
    for (int mi = 0; mi < MREP; ++mi)
#pragma unroll
      for (int ni = 0; ni < NREP; ++ni) {
        const int col = wn * (NREP * 16) + ni * 16 + lr;
        const float bv = biasf ? biasf[n0 + col] : 0.f;
#pragma unroll
        for (int j = 0; j < 4; ++j) {
          const int row = wm * (MREP * 16) + mi * 16 + (hi << 2) + j;
          cl[row * BN + ((((col >> 2) ^ (row & 7)) << 2) | (col & 3))] =
              acc[mi][ni][j] + bv;
        }
      }
    __syncthreads();
    constexpr int GPR = BN / 4;
    constexpr int PT = BM * GPR / THREADS;
#pragma unroll
    for (int c = 0; c < PT; ++c) {
      const int ch = c * THREADS + tid;
      const int row = ch / GPR, g = ch % GPR;
      f32x4 vv = *(const f32x4*)&cl[row * BN + ((g ^ (row & 7)) << 2)];
      *(f32x4*)&((float*)C0)[(size_t)(m0 + row) * N + n0 + g * 4] = vv;
    }
  }
}

// ---------------------------------------------------------------------------
// 2-phase pipelined GEMM + LDS-staged epilogue — conv1.
// AMODE 2: dual-tap padded rows (logical K = 2*Kh). OUTPAD: write padded o1p.
// ---------------------------------------------------------------------------
template <int WM, int WN, int MREP, int NREP, int AMODE, bool OUTPAD>
__global__ __launch_bounds__(WM * WN * 64, 2) void gemm_pipe(
    const bf16* __restrict__ A, const bf16* __restrict__ W, void* __restrict__ Cout,
    const float* __restrict__ bias, int M, int N, int K) {
  constexpr int BM = WM * MREP * 16;
  constexpr int BN = WN * NREP * 16;
  constexpr int THREADS = WM * WN * 64;
  constexpr int ROWS = BM + BN;
  constexpr int CHA = BM * 4 / THREADS;
  constexpr int CHB = BN * 4 / THREADS;
  static_assert(CHA + CHB == 4, "vmcnt ledger assumes 4 loads/thread/stage");
  __shared__ bf16 lds[4][ROWS * 32];
  static_assert(BM * BN * 2 <= sizeof(lds), "C tile must fit LDS for epilogue");

  const int nbx = N / BN;
  const int nwg = (M / BM) * nbx;
  const int wgid = (blockIdx.x & 7) * (nwg >> 3) + (blockIdx.x >> 3);
  const int bx = wgid % nbx, by = wgid / nbx;
  const int m0 = by * BM, n0 = bx * BN;
  const int tid = threadIdx.x;
  const int w = tid >> 6, l = tid & 63;
  const int wm = w / WN, wn = w % WN;
  const int lr = l & 15;
  const int hi = l >> 4;

  auto aAddr = [&](int row, int t) -> const bf16* {
    const int m = m0 + row;
    if constexpr (AMODE == 2) {
      const int Kh2 = K >> 1, nkh = Kh2 >> 5;
      const int tap = (t >= nkh) ? 1 : 0;
      return A + (size_t)((m >> 10) * SP + (m & 1023) + tap) * Kh2 +
             ((t - (tap ? nkh : 0)) << 5);
    } else {
      return A + (size_t)m * K + (t << 5);
    }
  };

  auto stage = [&](int slot, int t) {
    const int k0 = t << 5;
#pragma unroll
    for (int c = 0; c < CHA; ++c) {
      const int ch = c * THREADS + tid;
      const int row = ch >> 2, cg = ch & 3;
      const int gc = (cg ^ ((row >> 1) & 3)) << 3;
      async16(aAddr(row, t) + gc, (char*)&lds[slot][0] + ch * 16);
    }
#pragma unroll
    for (int c = 0; c < CHB; ++c) {
      const int ch = c * THREADS + tid;
      const int row = ch >> 2, cg = ch & 3;
      const int gc = (cg ^ ((row >> 1) & 3)) << 3;
      async16(W + (size_t)(n0 + row) * K + k0 + gc,
              (char*)&lds[slot][0] + (BM * 4 + ch) * 16);
    }
  };

  f32x4 acc[MREP][NREP] = {};
  const int nk = K >> 5;

  stage(0, 0);
  stage(1, 1);
  stage(2, 2);
  asm volatile("s_waitcnt vmcnt(8)" ::: "memory");
  __builtin_amdgcn_s_barrier();
  __builtin_amdgcn_sched_barrier(0);

  bf16x8 fAc[MREP], fBc[NREP], fAn[MREP], fBn[NREP];
  {
    const char* nb = (const char*)&lds[0][0];
#pragma unroll
    for (int mi = 0; mi < MREP; ++mi) {
      const int r = wm * (MREP * 16) + mi * 16 + lr;
      fAc[mi] = *(const bf16x8*)(nb + r * 64 + ((hi ^ ((r >> 1) & 3)) << 4));
    }
#pragma unroll
    for (int ni = 0; ni < NREP; ++ni) {
      const int r = BM + wn * (NREP * 16) + ni * 16 + lr;
      fBc[ni] = *(const bf16x8*)(nb + r * 64 + ((hi ^ ((r >> 1) & 3)) << 4));
    }
  }

#define GSTEP(T_, CA, CB, NA, NB)                                              \
  do {                                                                         \
    if ((T_) + 2 < nk) asm volatile("s_waitcnt vmcnt(4)" ::: "memory");        \
    else               asm volatile("s_waitcnt vmcnt(0)" ::: "memory");        \
    __builtin_amdgcn_s_barrier();                                              \
    __builtin_amdgcn_sched_barrier(0);                                         \
    if ((T_) + 3 < nk) stage(((T_) + 3) & 3, (T_) + 3);                        \
    if ((T_) + 1 < nk) {                                                       \
      const char* nb = (const char*)&lds[((T_) + 1) & 3][0];                   \
      _Pragma("unroll") for (int mi = 0; mi < MREP; ++mi) {                    \
        const int r = wm * (MREP * 16) + mi * 16 + lr;                         \
        NA[mi] = *(const bf16x8*)(nb + r * 64 + ((hi ^ ((r >> 1) & 3)) << 4)); \
      }                                                                        \
      _Pragma("unroll") for (int ni = 0; ni < NREP; ++ni) {                    \
        const int r = BM + wn * (NREP * 16) + ni * 16 + lr;                    \
        NB[ni] = *(const bf16x8*)(nb + r * 64 + ((hi ^ ((r >> 1) & 3)) << 4)); \
      }                                                                        \
    }                                                                          \
    __builtin_amdgcn_s_setprio(1);                                             \
    _Pragma("unroll") for (int mi = 0; mi < MREP; ++mi)                        \
      _Pragma("unroll") for (int ni = 0; ni < NREP; ++ni)                      \
        acc[mi][ni] =                                                          \
            __builtin_amdgcn_mfma_f32_16x16x32_bf16(CA[mi], CB[ni], acc[mi][ni], 0, 0, 0); \
    __builtin_amdgcn_s_setprio(0);                                             \
  } while (0)

  for (int t = 0; t < nk; t += 2) {
    GSTEP(t, fAc, fBc, fAn, fBn);
    GSTEP(t + 1, fAn, fBn, fAc, fBc);
  }
#undef GSTEP

  // ---- LDS-staged coalesced epilogue (bf16, optionally padded rows) ----
  __syncthreads();
  {
    bf16* cl = (bf16*)&lds[0][0];
#pragma unroll
    for (int mi = 0; mi < MREP; ++mi) {
#pragma unroll
      for (int ni = 0; ni < NREP; ++ni) {
        const int col = wn * (NREP * 16) + ni * 16 + lr;
        const float bv = bias ? bias[n0 + col] : 0.f;
#pragma unroll
        for (int j = 0; j < 4; ++j) {
          const int row = wm * (MREP * 16) + mi * 16 + (hi << 2) + j;
          cl[row * BN + ((((col >> 3) ^ (row & 7)) << 3) | (col & 7))] =
              (bf16)(acc[mi][ni][j] + bv);
        }
      }
    }
    __syncthreads();
    constexpr int GPR = BN / 8;
    constexpr int PT = BM * GPR / THREADS;
#pragma unroll
    for (int c = 0; c < PT; ++c) {
      const int ch = c * THREADS + tid;
      const int row = ch / GPR, g = ch % GPR;
      const int mr = m0 + row;
      const size_t orow = OUTPAD ? (size_t)((mr >> 10) * SP + (mr & 1023) + 1)
                                 : (size_t)mr;
      bf16x8 vv = *(const bf16x8*)&cl[row * BN + ((g ^ (row & 7)) << 3)];
      *(bf16x8*)&((bf16*)Cout)[orow * N + n0 + g * 8] = vv;
    }
  }
}

// ---------------------------------------------------------------------------
// k_prep: ONE kernel for all input prep:
//   - padded hsbp (B,S+1,H): row 0 = lf1, rows 1..S = bf16(hid)
//   - o1p row-0 prefill = lf2; trig table cst
//   - weight conversions (segmented per-thread tasks):
//       [0,2.10M)   Wqk f2b x4      -> WqkB (ws Wslot)
//       [2.10,3.15) Wv  f2b x4      -> WvB  (d_out scratch)
//       [3.15,4.19) c1w deint       -> W1d  (d_out scratch +8MB)
//       [4.19,5.24) c2w deint       -> W2d  (d_out scratch +16MB)
//   d_out-as-scratch is legal: fully overwritten by the final GEMM each call.
// ---------------------------------------------------------------------------
__global__ void k_prep(const float* __restrict__ hid, const float* __restrict__ lf1,
                       const float* __restrict__ lf2, const float* __restrict__ rot,
                       const float* __restrict__ Wqk, const float* __restrict__ Wv,
                       const float* __restrict__ c1w, const float* __restrict__ c2w,
                       bf16* __restrict__ hsbp, bf16* __restrict__ o1p,
                       f32x2* __restrict__ cst, bf16* __restrict__ WqkB,
                       bf16* __restrict__ WvB, bf16* __restrict__ W1d,
                       bf16* __restrict__ W2d) {
  int idx = blockIdx.x * 256 + threadIdx.x;  // < T*H = 8.4M
  // --- hsbp build ---
  {
    int t = idx >> 11, h = idx & 2047;
    int b = t >> 10, s = t & 1023;
    hsbp[((size_t)(b * SP + s + 1) << 11) + h] = (bf16)hid[idx];
    if (idx < Bc * Hc) {
      int bb = idx >> 11, hh = idx & 2047;
      hsbp[((size_t)(bb * SP) << 11) + hh] = (bf16)lf1[idx];
    }
    if (idx < Bc * 1024) {
      int bb = idx >> 10, cc = idx & 1023;
      o1p[((size_t)(bb * SP) << 10) + cc] = (bf16)lf2[idx];
    }
    if (idx < Sc * 64) {
      float f = rot[idx];
      f32x2 cs = {cosf(f), sinf(f)};
      cst[idx] = cs;
    }
  }
  // --- weight conversions (segments) ---
  if (idx < 2097152) {                     // Wqk: 8.4M f32, x4
    float4 v = ((const float4*)Wqk)[idx];
    bf16x4 o = {(bf16)v.x, (bf16)v.y, (bf16)v.z, (bf16)v.w};
    ((bf16x4*)WqkB)[idx] = o;
  } else if (idx < 3145728) {              // Wv: 4.2M f32, x4
    int j = idx - 2097152;
    float4 v = ((const float4*)Wv)[j];
    bf16x4 o = {(bf16)v.x, (bf16)v.y, (bf16)v.z, (bf16)v.w};
    ((bf16x4*)WvB)[j] = o;
  } else if (idx < 4194304) {              // c1w deint: O=1024, Hd=2048
    int j = idx - 3145728;                 // j < 1024*1024
    int o = j >> 10, h0 = (j & 1023) * 2;
    float4 v = *(const float4*)&c1w[(size_t)o * 4096 + h0 * 2];
    bf16x2 t0 = {(bf16)v.x, (bf16)v.z};
    bf16x2 t1 = {(bf16)v.y, (bf16)v.w};
    *(bf16x2*)&W1d[(size_t)o * 4096 + h0] = t0;
    *(bf16x2*)&W1d[(size_t)o * 4096 + 2048 + h0] = t1;
  } else if (idx < 5242880) {              // c2w deint: O=2048, Hd=1024
    int j = idx - 4194304;                 // j < 2048*512
    int o = j >> 9, h0 = (j & 511) * 2;
    float4 v = *(const float4*)&c2w[(size_t)o * 2048 + h0 * 2];
    bf16x2 t0 = {(bf16)v.x, (bf16)v.z};
    bf16x2 t1 = {(bf16)v.y, (bf16)v.w};
    *(bf16x2*)&W2d[(size_t)o * 2048 + h0] = t0;
    *(bf16x2*)&W2d[(size_t)o * 2048 + 1024 + h0] = t1;
  }
}

// ---------------------------------------------------------------------------
// lf = rmsnorm(o2 + x) * g   (one block per row, 256 thr x 8 elems).
// R16: residual x read from padded bf16 hsbp (saves 16MB fp32 hid re-read;
// bf16 rounding of x is within existing error budget). Also folds the Wo
// fp32->bf16 conversion (1M float4 items, exactly 1 per thread) into this
// kernel, writing WoB (the dead o1p region) — removes the k_f2b4 launch.
// ---------------------------------------------------------------------------
__global__ __launch_bounds__(256) void k_rmsnorm(const bf16* __restrict__ o2,
                                                 const bf16* __restrict__ hsbp,
                                                 const float* __restrict__ g,
                                                 bf16* __restrict__ lf,
                                                 const float* __restrict__ Wo,
                                                 bf16* __restrict__ WoB) {
  int t = blockIdx.x, tid = threadIdx.x;
  // fused Wo conversion: idx in [0, 1M), 1:1 with float4 items of Wo
  {
    int idx = t * 256 + tid;
    float4 v = ((const float4*)Wo)[idx];
    bf16x4 o = {(bf16)v.x, (bf16)v.y, (bf16)v.z, (bf16)v.w};
    ((bf16x4*)WoB)[idx] = o;
  }
  size_t base = ((size_t)t << 11) + tid * 8;
  size_t hbase = (((size_t)((t >> 10) * SP + (t & 1023) + 1)) << 11) + tid * 8;
  bf16x8 ov = *(const bf16x8*)&o2[base];
  bf16x8 hv = *(const bf16x8*)&hsbp[hbase];
  float vals[8];
  float ss = 0.f;
#pragma unroll
  for (int i = 0; i < 8; ++i) {
    float x = (float)ov[i] + (float)hv[i];
    vals[i] = x;
    ss += x * x;
  }
#pragma unroll
  for (int off = 1; off < 64; off <<= 1) ss += __shfl_xor(ss, off);
  __shared__ float red[4];
  if ((tid & 63) == 0) red[tid >> 6] = ss;
  __syncthreads();
  float tot = red[0] + red[1] + red[2] + red[3];
  float inv = rsqrtf(tot * (1.f / 2048.f) + 1e-6f);
  bf16x8 o;
#pragma unroll
  for (int i = 0; i < 8; ++i) o[i] = (bf16)(vals[i] * inv * g[tid * 8 + i]);
  *(bf16x8*)&lf[base] = o;
}

// ---------------------------------------------------------------------------
// causal flash attention v3: LDS-staged K/V (dbuf), balanced q-tile pairs,
// XCD-local (b,h) mapping, setprio around MFMA clusters, defer-max (THR=8).
// ---------------------------------------------------------------------------
__global__ __launch_bounds__(256, 2) void k_attn(const bf16* __restrict__ qr,
                                                 const bf16* __restrict__ kr,
                                                 const bf16* __restrict__ vT,
                                                 bf16* __restrict__ att) {
  __shared__ bf16 Ks[2][64 * 128];
  __shared__ bf16 Vs[2][128 * 64];
  __shared__ bf16 plds[4][16 * 64];
  const int bid = blockIdx.x;
  const int xcd = bid & 7, jj = bid >> 3;
  const int bn = xcd * 8 + (jj >> 3);
  const int pr = jj & 7;
  const int tid = threadIdx.x, w = tid >> 6, l = tid & 63;
  const int lr = l & 15, hi = l >> 4;
  const bf16* kb = kr + ((size_t)bn << 17);
  const bf16* vb = vT + ((size_t)bn << 17);
  const int b = bn >> 4, hh = bn & 15;
  const float scaling = 0.08838834764831845f;
  const float THR = 8.f;

  auto stage = [&](int buf, int kt) {
#pragma unroll
    for (int c = 0; c < 4; ++c) {
      int chunk = c * 256 + tid;
      int prow = chunk >> 4, pcg = chunk & 15;
      async16(kb + ((size_t)(kt * 64 + prow) << 7) + ((pcg ^ (prow & 7)) << 3),
              (char*)&Ks[buf][0] + chunk * 16);
    }
#pragma unroll
    for (int c = 0; c < 4; ++c) {
      int chunk = c * 256 + tid;
      int prow = chunk >> 3, pcg = chunk & 7;
      async16(vb + ((size_t)prow << 10) + kt * 64 + ((pcg ^ (prow & 7)) << 3),
              (char*)&Vs[buf][0] + chunk * 16);
    }
  };

#pragma unroll 1
  for (int phase = 0; phase < 2; ++phase) {
    const int qt = phase ? (15 - pr) : pr;
    const int qg0 = qt * 64 + w * 16;
    const bf16* qb = qr + ((size_t)(bn * 1024 + qg0) << 7);
    bf16x8 qf[4];
#pragma unroll
    for (int ks = 0; ks < 4; ++ks) qf[ks] = *(const bf16x8*)&qb[lr * 128 + ks * 32 + hi * 8];
    f32x4 oacc[8] = {};
    float mrow[4] = {-1e30f, -1e30f, -1e30f, -1e30f};
    float lrow[4] = {0.f, 0.f, 0.f, 0.f};
    const int nkb = qt + 1;

    stage(0, 0);
    __syncthreads();

    for (int kbt = 0; kbt < nkb; ++kbt) {
      const int cur = kbt & 1;
      if (kbt + 1 < nkb) stage(cur ^ 1, kbt + 1);

      f32x4 sacc[4] = {};
      __builtin_amdgcn_s_setprio(1);
#pragma unroll
      for (int n = 0; n < 4; ++n) {
        const int krow = n * 16 + lr;
#pragma unroll
        for (int ks = 0; ks < 4; ++ks) {
          bf16x8 kf = *(const bf16x8*)&Ks[cur][(krow << 7) + ((((ks << 2) | hi) ^ (krow & 7)) << 3)];
          sacc[n] = __builtin_amdgcn_mfma_f32_16x16x32_bf16(qf[ks], kf, sacc[n], 0, 0, 0);
        }
      }
      __builtin_amdgcn_s_setprio(0);
      const bool needmask = (kbt * 64 + 63 > qg0);
#pragma unroll
      for (int n = 0; n < 4; ++n) {
        int kg = kbt * 64 + n * 16 + lr;
#pragma unroll
        for (int j = 0; j < 4; ++j) {
          float sv = sacc[n][j] * scaling;
          if (needmask && kg > qg0 + hi * 4 + j) sv = -1e30f;
          sacc[n][j] = sv;
        }
      }
      float pm[4];
#pragma unroll
      for (int j = 0; j < 4; ++j) {
        float p = fmaxf(fmaxf(sacc[0][j], sacc[1][j]), fmaxf(sacc[2][j], sacc[3][j]));
        p = fmaxf(p, __shfl_xor(p, 1));
        p = fmaxf(p, __shfl_xor(p, 2));
        p = fmaxf(p, __shfl_xor(p, 4));
        p = fmaxf(p, __shfl_xor(p, 8));
        pm[j] = p;
      }
      float sf[4] = {1.f, 1.f, 1.f, 1.f};
      bool needup = (pm[0] > mrow[0] + THR) || (pm[1] > mrow[1] + THR) ||
                    (pm[2] > mrow[2] + THR) || (pm[3] > mrow[3] + THR);
      if (__any(needup)) {
#pragma unroll
        for (int j = 0; j < 4; ++j) {
          float mn = fmaxf(mrow[j], pm[j]);
          sf[j] = __expf(mrow[j] - mn);
          mrow[j] = mn;
        }
#pragma unroll
        for (int dt = 0; dt < 8; ++dt)
#pragma unroll
          for (int j = 0; j < 4; ++j) oacc[dt][j] *= sf[j];
      }
#pragma unroll
      for (int n = 0; n < 4; ++n)
#pragma unroll
        for (int j = 0; j < 4; ++j) sacc[n][j] = __expf(sacc[n][j] - mrow[j]);
#pragma unroll
      for (int j = 0; j < 4; ++j) {
        float ps = sacc[0][j] + sacc[1][j] + sacc[2][j] + sacc[3][j];
        ps += __shfl_xor(ps, 1);
        ps += __shfl_xor(ps, 2);
        ps += __shfl_xor(ps, 4);
        ps += __shfl_xor(ps, 8);
        lrow[j] = lrow[j] * sf[j] + ps;
      }
#pragma unroll
      for (int n = 0; n < 4; ++n)
#pragma unroll
        for (int j = 0; j < 4; ++j)
          plds[w][(hi * 4 + j) * 64 + n * 16 + lr] = (bf16)sacc[n][j];
      asm volatile("s_waitcnt lgkmcnt(0)" ::: "memory");
      __builtin_amdgcn_s_setprio(1);
#pragma unroll
      for (int ks2 = 0; ks2 < 2; ++ks2) {
        bf16x8 pf = *(const bf16x8*)&plds[w][lr * 64 + ks2 * 32 + hi * 8];
#pragma unroll
        for (int dt = 0; dt < 8; ++dt) {
          const int vrow = dt * 16 + lr;
          bf16x8 vf = *(const bf16x8*)&Vs[cur][(vrow << 6) + ((((ks2 << 2) | hi) ^ (lr & 7)) << 3)];
          oacc[dt] = __builtin_amdgcn_mfma_f32_16x16x32_bf16(pf, vf, oacc[dt], 0, 0, 0);
        }
      }
      __builtin_amdgcn_s_setprio(0);
      __syncthreads();
    }

#pragma unroll
    for (int j = 0; j < 4; ++j) {
      float inv = 1.f / lrow[j];
      int qg = qg0 + hi * 4 + j;
      size_t obase = ((size_t)(b * 1024 + qg) << 11) + hh * 128;
#pragma unroll
      for (int dt = 0; dt < 8; ++dt) att[obase + dt * 16 + lr] = (bf16)(oacc[dt][j] * inv);
    }
  }
}

// ---------------------------------------------------------------------------
// Workspace plan (~124 MB ws + d_out scratch):
//   ws  0-16   WqkB
//   ws 16-34   hsbp [live until rmsnorm residual] -> att (written at attn)
//   ws 34-43   o1p  [dead after conv2] -> WoB (written by k_rmsnorm, 8MB)
//   ws 43-59   o2 | 59-75 lfb | 75-91 vT | 91-107 qr | 107-123 kr | 123 cst
//   d_out 0-8  WvB | 8-16 W1d | 16-24 W2d   (scratch; final GEMM overwrites)
// Dispatches (8): prep, Wv, conv1, conv2, rmsnorm+Wo-conv, Wqk, attn, Wo.
// ---------------------------------------------------------------------------
extern "C" void kernel_launch(void* const* d_in, const int* in_sizes, int n_in,
                              void* d_out, int out_size, void* d_ws, size_t ws_size,
                              hipStream_t stream) {
  const float* hid = (const float*)d_in[1];
  const float* rot = (const float*)d_in[2];
  const float* lf1 = (const float*)d_in[3];
  const float* lf2 = (const float*)d_in[4];
  const float* Wqk = (const float*)d_in[5];
  const float* Wv  = (const float*)d_in[6];
  const float* Wo  = (const float*)d_in[7];
  const float* c1w = (const float*)d_in[8];
  const float* c2w = (const float*)d_in[10];
  const float* c1b = (const float*)d_in[9];
  const float* c2b = (const float*)d_in[11];
  const float* lng = (const float*)d_in[12];
  float* outp = (float*)d_out;
  char* ws = (char*)d_ws;
  char* od = (char*)d_out;

  const size_t MB = 1ull << 20;
  bf16* Wslot = (bf16*)(ws + 0 * MB);    // WqkB
  bf16* hsbp  = (bf16*)(ws + 16 * MB);
  bf16* att   = (bf16*)(ws + 16 * MB);   // alias (hsbp dead after rmsnorm)
  bf16* o1p   = (bf16*)(ws + 34 * MB);
  bf16* WoB   = (bf16*)(ws + 34 * MB);   // alias (o1p dead after conv2)
  bf16* o2    = (bf16*)(ws + 43 * MB);
  bf16* lfb   = (bf16*)(ws + 59 * MB);
  bf16* vT    = (bf16*)(ws + 75 * MB);
  bf16* qr    = (bf16*)(ws + 91 * MB);
  bf16* kr    = (bf16*)(ws + 107 * MB);
  f32x2* cst  = (f32x2*)(ws + 123 * MB);
  // d_out scratch (fully overwritten by final GEMM each call)
  bf16* WvB   = (bf16*)(od + 0 * MB);    // 8 MB
  bf16* W1d   = (bf16*)(od + 8 * MB);    // 8 MB
  bf16* W2d   = (bf16*)(od + 16 * MB);   // 8 MB

  // 0. ONE prep kernel: padded inputs + trig + 4 weight conversions
  k_prep<<<Tc * Hc / 256, 256, 0, stream>>>(hid, lf1, lf2, rot, Wqk, Wv, c1w, c2w,
                                            hsbp, o1p, cst, Wslot, WvB, W1d, W2d);

  // 1. v = hs @ Wv.T (padded rows), fused V-transpose -> vT (128^2, 2/CU)
  gemm8<2, 2, 4, 4, 1, 1><<<512, 256, 0, stream>>>(hsbp, WvB, vT, nullptr, nullptr,
                                                   nullptr, Tc, Pc, Hc);

  // 2. conv1: dual-tap GEMM (logical K=4096 over hsbp taps) -> padded o1p
  gemm_pipe<2, 2, 4, 4, 2, true><<<256, 256, 0, stream>>>(hsbp, W1d, o1p, c1b,
                                                          Tc, 1024, 4096);

  // 3. conv2: dual-tap GEMM (logical K=2048 over o1p taps) -> o2 (128^2)
  gemm8<2, 2, 4, 4, 0, 2><<<512, 256, 0, stream>>>(o1p, W2d, o2, nullptr, c2b,
                                                   nullptr, Tc, 2048, 2048);

  // 4. residual (from bf16 hsbp) + rmsnorm, fused Wo f2b -> WoB (o1p region)
  k_rmsnorm<<<Tc, 256, 0, stream>>>(o2, hsbp, lng, lfb, Wo, WoB);

  // 5. qk projection (256^2, 512 thr), fused RoPE epilogue -> qr, kr
  gemm8<2, 4, 8, 4, 2, 0><<<256, 512, 0, stream>>>(lfb, Wslot, qr, kr, nullptr, cst,
                                                   Tc, 4096, Hc);

  // 6. attention
  k_attn<<<Bc * NHc * 8, 256, 0, stream>>>(qr, kr, vT, att);

  // 7. output projection (fp32 out; overwrites d_out scratch; 128^2)
  gemm8<2, 2, 4, 4, 3, 0><<<512, 256, 0, stream>>>(att, WoB, outp, nullptr, nullptr,
                                                   nullptr, Tc, 2048, 2048);
}